// Round 3
// baseline (3115.966 us; speedup 1.0000x reference)
//
#include <hip/hip_runtime.h>
#include <math.h>

namespace {
constexpr int NC = 4;      // chunks
constexpr int CL = 1024;   // chunk length
constexpr int NH = 8;      // heads
constexpr int ND = 64;     // head dim
constexpr float KSCALE = 0.125f;
constexpr float KEPS = 1e-6f;
}

// ---------------------------------------------------------------------------
// gate_kernel: per (c,h) inclusive cumsum of log_g over chunk; precompute
// qdh = exp(g/2), qd = exp(g), iqd = exp(-g), wk = exp(g_end - g),
// gtot = exp(g_end).
// ---------------------------------------------------------------------------
__global__ __launch_bounds__(1024) void gate_kernel(const float* __restrict__ log_g,
    float* __restrict__ qdh, float* __restrict__ qd, float* __restrict__ iqd,
    float* __restrict__ wk, float* __restrict__ gtot) {
  int c = blockIdx.x / NH, h = blockIdx.x % NH;
  int l = threadIdx.x;
  __shared__ float sm[CL];
  sm[l] = log_g[(c*CL + l)*NH + h];
  __syncthreads();
  for (int off = 1; off < CL; off <<= 1) {
    float t = (l >= off) ? sm[l - off] : 0.0f;
    __syncthreads();
    sm[l] += t;
    __syncthreads();
  }
  float g = sm[l];
  float gend = sm[CL - 1];
  int base = (c*NH + h)*CL + l;
  qdh[base] = expf(0.5f * g);
  qd[base]  = expf(g);
  iqd[base] = expf(-g);
  wk[base]  = expf(gend - g);
  if (l == 0) gtot[c*NH + h] = expf(gend);
}

// ---------------------------------------------------------------------------
// intra_kernel: causal intra-chunk attention.
// A[r,s] = exp(g_r - g_s) * (qs_r . k_s)^2 for s<=r, intra = A@V, row = A.sum
// Block: 64 q-rows, loop over 32-wide s tiles. 256 threads.
// ---------------------------------------------------------------------------
__global__ __launch_bounds__(256) void intra_kernel(const float* __restrict__ q,
    const float* __restrict__ k, const float* __restrict__ v,
    const float* __restrict__ qd, const float* __restrict__ iqd,
    float* __restrict__ out, float* __restrict__ row) {
  int rt = blockIdx.x;   // row tile (64 rows), 0..15
  int h = blockIdx.y, c = blockIdx.z;
  __shared__ float qt[64][65];
  __shared__ float kt[32][65];
  __shared__ float vt[32][65];
  __shared__ float At[64][33];
  __shared__ float qdr[64], iqds[32];
  int tid = threadIdx.x;
  int gbase = (c*NH + h)*CL;
  // load q tile (scaled)
  for (int it = 0; it < 16; ++it) {
    int elem = it*256 + tid;
    int rr = elem >> 6, dd = elem & 63;
    qt[rr][dd] = KSCALE * q[((c*CL + rt*64 + rr)*NH + h)*ND + dd];
  }
  if (tid < 64) qdr[tid] = qd[gbase + rt*64 + tid];
  float acc[16];
  #pragma unroll
  for (int i = 0; i < 16; ++i) acc[i] = 0.f;
  float rowsum = 0.f;
  int r2 = tid >> 2, vg = tid & 3;
  int nst = 2*rt + 2;  // number of 32-wide s tiles (covers s <= rt*64+63)
  for (int st = 0; st < nst; ++st) {
    for (int it = 0; it < 8; ++it) {
      int elem = it*256 + tid;
      int ss = elem >> 6, dd = elem & 63;
      int gidx = ((c*CL + st*32 + ss)*NH + h)*ND + dd;
      kt[ss][dd] = k[gidx];
      vt[ss][dd] = v[gidx];
    }
    if (tid < 32) iqds[tid] = iqd[gbase + st*32 + tid];
    __syncthreads();
    // phase 1: scores -> At
    for (int it = 0; it < 8; ++it) {
      int elem = it*256 + tid;
      int rr = elem >> 5, ss = elem & 31;
      float dot = 0.f;
      #pragma unroll
      for (int dd = 0; dd < 64; ++dd) dot += qt[rr][dd] * kt[ss][dd];
      int rg = rt*64 + rr, sg = st*32 + ss;
      float a = 0.f;
      if (sg <= rg) a = qdr[rr] * iqds[ss] * dot * dot;
      At[rr][ss] = a;
    }
    __syncthreads();
    // phase 2: acc += A @ V, rowsum
    #pragma unroll 4
    for (int ss = 0; ss < 32; ++ss) {
      float a = At[r2][ss];
      if (vg == 0) rowsum += a;
      #pragma unroll
      for (int i = 0; i < 16; ++i) acc[i] += a * vt[ss][vg*16 + i];
    }
    __syncthreads();
  }
  int ob = ((c*CL + rt*64 + r2)*NH + h)*ND + vg*16;
  #pragma unroll
  for (int i = 0; i < 16; ++i) out[ob + i] = acc[i];
  if (vg == 0) row[gbase + rt*64 + r2] = rowsum;
}

// ---------------------------------------------------------------------------
// pz_kernel (per chunk c): S[h,d,e,v] = gtot*S + sum_l wk_l k[l,d] k[l,e] v[l,v]
//                          sk[h,d,e]  = gtot*sk + sum_l wk_l k[l,d] k[l,e]
// Block per (d,h): computes full [e=64][v=64] slab for its d.
// ---------------------------------------------------------------------------
__global__ __launch_bounds__(256) void pz_kernel(const float* __restrict__ k,
    const float* __restrict__ v, const float* __restrict__ wk,
    const float* __restrict__ gtot, float* __restrict__ S,
    float* __restrict__ sk, int c) {
  int d = blockIdx.x, h = blockIdx.y;
  __shared__ float kt[64][65];
  __shared__ float vt[64][65];
  __shared__ float coef[64];
  int tid = threadIdx.x;
  float acc[16];
  #pragma unroll
  for (int i = 0; i < 16; ++i) acc[i] = 0.f;
  float zacc = 0.f;
  int e = tid >> 2, vg = tid & 3;
  for (int lt = 0; lt < 16; ++lt) {
    for (int it = 0; it < 16; ++it) {
      int elem = it*256 + tid;
      int ll = elem >> 6, dd = elem & 63;
      int gidx = ((c*CL + lt*64 + ll)*NH + h)*ND + dd;
      kt[ll][dd] = k[gidx];
      vt[ll][dd] = v[gidx];
    }
    __syncthreads();
    if (tid < 64) coef[tid] = kt[tid][d] * wk[(c*NH + h)*CL + lt*64 + tid];
    __syncthreads();
    #pragma unroll 4
    for (int l = 0; l < 64; ++l) {
      float a = coef[l] * kt[l][e];
      if (vg == 0) zacc += a;
      #pragma unroll
      for (int i = 0; i < 16; ++i) acc[i] += a * vt[l][vg*16 + i];
    }
    __syncthreads();
  }
  float gt = gtot[c*NH + h];
  size_t sbase = ((size_t)(h*ND + d)*ND + e)*ND + vg*16;
  #pragma unroll
  for (int i = 0; i < 16; ++i) S[sbase + i] = gt * S[sbase + i] + acc[i];
  if (vg == 0) {
    int zb = (h*ND + d)*ND + e;
    sk[zb] = gt * sk[zb] + zacc;
  }
}

// ---------------------------------------------------------------------------
// inter_kernel (per chunk c): uses CURRENT S (state before this chunk).
// inter[r,v] = sum_de phi[r,de] S[de,v], phi[r,de] = qh[r,d]*qh[r,e]
// where qh = q*SCALE*exp(g/2). den_i = phi . sk. Fuses final divide:
// out = (intra + inter) / max(row + den_i, eps).
// Within a 64-wide de chunk dc, d == dc constant and e == kk.
// ---------------------------------------------------------------------------
__global__ __launch_bounds__(256) void inter_kernel(const float* __restrict__ q,
    const float* __restrict__ qdh, const float* __restrict__ S,
    const float* __restrict__ sk, const float* __restrict__ row,
    float* __restrict__ out, int c) {
  int rt = blockIdx.x;  // 0..31, 32 rows each
  int h = blockIdx.y;
  __shared__ float qt[32][65];
  __shared__ float St[64][65];
  __shared__ float skt[64];
  __shared__ float denr[32];
  __shared__ float qdl[32];
  int tid = threadIdx.x;
  if (tid < 32) qdl[tid] = qdh[(c*NH + h)*CL + rt*32 + tid];
  __syncthreads();
  for (int it = 0; it < 8; ++it) {
    int elem = it*256 + tid;
    int rr = elem >> 6, dd = elem & 63;
    qt[rr][dd] = KSCALE * qdl[rr] * q[((c*CL + rt*32 + rr)*NH + h)*ND + dd];
  }
  __syncthreads();
  float acc[8];
  #pragma unroll
  for (int i = 0; i < 8; ++i) acc[i] = 0.f;
  float den = 0.f;
  int r2 = tid >> 3, vg = tid & 7;
  for (int dc = 0; dc < 64; ++dc) {
    for (int it = 0; it < 16; ++it) {
      int elem = it*256 + tid;
      int rr = elem >> 6, vv = elem & 63;
      St[rr][vv] = S[(size_t)h*262144 + (size_t)(dc*64 + rr)*64 + vv];
    }
    if (tid < 64) skt[tid] = sk[h*4096 + dc*64 + tid];
    __syncthreads();
    float qc = qt[r2][dc];
    #pragma unroll 4
    for (int kk = 0; kk < 64; ++kk) {
      float a = qc * qt[r2][kk];
      if (vg == 0) den += a * skt[kk];
      #pragma unroll
      for (int i = 0; i < 8; ++i) acc[i] += a * St[kk][vg*8 + i];
    }
    __syncthreads();
  }
  if (vg == 0) denr[r2] = den;
  __syncthreads();
  float dfull = fmaxf(row[(c*NH + h)*CL + rt*32 + r2] + denr[r2], KEPS);
  int ob = ((c*CL + rt*32 + r2)*NH + h)*ND + vg*8;
  #pragma unroll
  for (int i = 0; i < 8; ++i) out[ob + i] = (out[ob + i] + acc[i]) / dfull;
}

// ---------------------------------------------------------------------------
extern "C" void kernel_launch(void* const* d_in, const int* in_sizes, int n_in,
                              void* d_out, int out_size, void* d_ws, size_t ws_size,
                              hipStream_t stream) {
  const float* q     = (const float*)d_in[0];
  const float* k     = (const float*)d_in[1];
  const float* v     = (const float*)d_in[2];
  const float* log_g = (const float*)d_in[3];
  float* out = (float*)d_out;
  float* ws = (float*)d_ws;

  const int CHL = NC * NH * CL;   // 32768
  float* qdh  = ws;
  float* qd   = ws + CHL;
  float* iqd  = ws + 2*CHL;
  float* wk   = ws + 3*CHL;
  float* row  = ws + 4*CHL;
  float* gtot = ws + 5*CHL;
  float* S    = ws + 5*CHL + 64;                 // H*D^3 floats
  float* sk   = S + (size_t)NH*ND*ND*ND;         // H*D^2 floats

  // zero the running state (ws is poisoned before every launch)
  hipMemsetAsync(S, 0, ((size_t)NH*ND*ND*ND + NH*ND*ND)*sizeof(float), stream);

  gate_kernel<<<dim3(NC*NH), dim3(CL), 0, stream>>>(log_g, qdh, qd, iqd, wk, gtot);
  intra_kernel<<<dim3(16, NH, NC), dim3(256), 0, stream>>>(q, k, v, qd, iqd, out, row);
  for (int c = 0; c < NC; ++c) {
    inter_kernel<<<dim3(32, NH), dim3(256), 0, stream>>>(q, qdh, S, sk, row, out, c);
    pz_kernel<<<dim3(ND, NH), dim3(256), 0, stream>>>(k, v, wk, gtot, S, sk, c);
  }
}

// Round 5
// 291.050 us; speedup vs baseline: 10.7060x; 10.7060x over previous
//
#include <hip/hip_runtime.h>
#include <math.h>

typedef float f32x4 __attribute__((ext_vector_type(4)));
typedef __bf16 bf16x8 __attribute__((ext_vector_type(8)));
typedef __bf16 bf16x4 __attribute__((ext_vector_type(4)));

namespace {
constexpr int NC = 4, CL = 1024, NH = 8, ND = 64;
constexpr float KSCALE = 0.125f, KEPS = 1e-6f;
constexpr int PQ = 72;   // LDS pitch (bf16) for [*][64] tiles: 144B rows, 16B-aligned
constexpr int PK = 40;   // LDS pitch (bf16) for [*][32] tiles: 80B rows, 16B-aligned
}

#define MFMA(a,b,c) __builtin_amdgcn_mfma_f32_16x16x32_bf16((a),(b),(c),0,0,0)

// ---------------------------------------------------------------------------
// gate: per (c,h) inclusive cumsum of log_g; write g, g_end, exp(g_end)
// ---------------------------------------------------------------------------
__global__ __launch_bounds__(1024) void gate_kernel(const float* __restrict__ lg,
    float* __restrict__ g_arr, float* __restrict__ gend, float* __restrict__ gtot) {
  int c = blockIdx.x >> 3, h = blockIdx.x & 7;
  int l = threadIdx.x;
  __shared__ float sm[CL];
  sm[l] = lg[(c*CL + l)*NH + h];
  __syncthreads();
  for (int off = 1; off < CL; off <<= 1) {
    float t = (l >= off) ? sm[l-off] : 0.f;
    __syncthreads();
    sm[l] += t;
    __syncthreads();
  }
  g_arr[(c*NH + h)*CL + l] = sm[l];
  if (l == 0) { gend[c*NH+h] = sm[CL-1]; gtot[c*NH+h] = expf(sm[CL-1]); }
}

// ---------------------------------------------------------------------------
// convert: bf16 operand arrays.
//   qgb[ch][l][d] = q*SCALE*exp(g/2)        (intra QK B-op, inter A-gen)
//   kgb[ch][l][d] = k*exp(-g/2)             (intra QK A-op)
//   kht[ch][d][l] = k*exp((gend-g)/2)       (pzscan A-gen, transposed)
//   vt [ch][p][l] p<64: v^T; p=64: ones; p=65..79: zeros  (B-op everywhere)
// ---------------------------------------------------------------------------
__global__ __launch_bounds__(256) void convert_kernel(const float* __restrict__ q,
    const float* __restrict__ k, const float* __restrict__ v,
    const float* __restrict__ g_arr, const float* __restrict__ gend,
    __bf16* __restrict__ qgb, __bf16* __restrict__ kgb,
    __bf16* __restrict__ kht, __bf16* __restrict__ vt) {
  int lt = blockIdx.x, h = blockIdx.y, c = blockIdx.z;
  int ch = c*NH + h;
  int t = threadIdx.x;
  __shared__ float ld[64][65];
  int lr = t >> 2, sg = t & 3;
  int l = lt*64 + lr;
  size_t ib = ((size_t)(c*CL + l)*NH + h)*ND + sg*16;
  float ge = gend[ch];
  float gl = g_arr[ch*CL + l];
  float eq = expf(0.5f*gl), ekk = expf(-0.5f*gl), ew = expf(0.5f*(ge-gl));
  float qv[16], kv[16], vv[16];
  #pragma unroll
  for (int i = 0; i < 4; ++i) {
    *(f32x4*)&qv[4*i] = *(const f32x4*)&q[ib+4*i];
    *(f32x4*)&kv[4*i] = *(const f32x4*)&k[ib+4*i];
    *(f32x4*)&vv[4*i] = *(const f32x4*)&v[ib+4*i];
  }
  size_t ob = ((size_t)ch*CL + l)*ND + sg*16;
  {
    bf16x8 a, b;
    #pragma unroll
    for (int i = 0; i < 8; ++i) { a[i]=(__bf16)(qv[i]*KSCALE*eq); b[i]=(__bf16)(qv[8+i]*KSCALE*eq); }
    *(bf16x8*)&qgb[ob] = a; *(bf16x8*)&qgb[ob+8] = b;
    #pragma unroll
    for (int i = 0; i < 8; ++i) { a[i]=(__bf16)(kv[i]*ekk); b[i]=(__bf16)(kv[8+i]*ekk); }
    *(bf16x8*)&kgb[ob] = a; *(bf16x8*)&kgb[ob+8] = b;
  }
  // kht transpose via LDS
  #pragma unroll
  for (int i = 0; i < 16; ++i) ld[lr][sg*16+i] = kv[i]*ew;
  __syncthreads();
  {
    int d = t >> 2, s2 = t & 3;
    bf16x8 a, b;
    #pragma unroll
    for (int i = 0; i < 8; ++i) { a[i]=(__bf16)ld[s2*16+i][d]; b[i]=(__bf16)ld[s2*16+8+i][d]; }
    size_t kb = ((size_t)ch*ND + d)*CL + lt*64 + s2*16;
    *(bf16x8*)&kht[kb] = a; *(bf16x8*)&kht[kb+8] = b;
  }
  __syncthreads();
  // vt transpose via LDS
  #pragma unroll
  for (int i = 0; i < 16; ++i) ld[lr][sg*16+i] = vv[i];
  __syncthreads();
  {
    int p = t >> 2, s2 = t & 3;
    bf16x8 a, b;
    #pragma unroll
    for (int i = 0; i < 8; ++i) { a[i]=(__bf16)ld[s2*16+i][p]; b[i]=(__bf16)ld[s2*16+8+i][p]; }
    size_t vb = ((size_t)ch*80 + p)*CL + lt*64 + s2*16;
    *(bf16x8*)&vt[vb] = a; *(bf16x8*)&vt[vb+8] = b;
  }
  if (t < 64) vt[((size_t)ch*80 + 64)*CL + lt*64 + t] = (__bf16)1.0f;
  for (int idx = t; idx < 15*64; idx += 256)
    vt[((size_t)ch*80 + 65 + idx/64)*CL + lt*64 + (idx & 63)] = (__bf16)0.0f;
}

// ---------------------------------------------------------------------------
// intra: causal. score=(qg.kg)^2 (gating prefolded). Swapped mfma(kg,qg)->S^T,
// square+mask, per-wave LDS bounce, A@V with vt (col64=rowsum).
// c==0: fuse divide (den_i=0). c>0: store raw num + row.
// ---------------------------------------------------------------------------
__global__ __launch_bounds__(256) void intra_kernel(const __bf16* __restrict__ qgb,
    const __bf16* __restrict__ kgb, const __bf16* __restrict__ vt,
    float* __restrict__ out, float* __restrict__ rowp) {
  int rt = blockIdx.x, h = blockIdx.y, c = blockIdx.z;
  int ch = c*NH + h;
  int t = threadIdx.x, wv = t >> 6, lane = t & 63, qq = lane >> 4, lm = lane & 15;
  __shared__ __align__(16) __bf16 qt[64*PQ];
  __shared__ __align__(16) __bf16 kgl[32*PQ];
  __shared__ __align__(16) __bf16 vtl[80*PK];
  __shared__ __align__(16) __bf16 As[64*PK];
  {
    int r = t >> 2, sg = t & 3;
    size_t gb = ((size_t)ch*CL + rt*64 + r)*ND + sg*16;
    *(bf16x8*)&qt[r*PQ + sg*16]     = *(const bf16x8*)&qgb[gb];
    *(bf16x8*)&qt[r*PQ + sg*16 + 8] = *(const bf16x8*)&qgb[gb+8];
  }
  __syncthreads();
  bf16x8 bq0 = *(bf16x8*)&qt[(wv*16+lm)*PQ + qq*8];
  bf16x8 bq1 = *(bf16x8*)&qt[(wv*16+lm)*PQ + 32 + qq*8];
  f32x4 acc[5];
  #pragma unroll
  for (int n = 0; n < 5; ++n) acc[n] = (f32x4){0.f,0.f,0.f,0.f};
  int r_gc = rt*64 + wv*16 + lm;
  int nst = 2*rt + 2;
  for (int s3 = 0; s3 < nst; ++s3) {
    __syncthreads();
    {
      int r = t >> 3, sg = t & 7;
      *(bf16x8*)&kgl[r*PQ + sg*8] =
        *(const bf16x8*)&kgb[((size_t)ch*CL + s3*32 + r)*ND + sg*8];
      int r2 = t >> 2, s2 = t & 3;
      *(bf16x8*)&vtl[r2*PK + s2*8] =
        *(const bf16x8*)&vt[((size_t)ch*80 + r2)*CL + s3*32 + s2*8];
      if (t < 64)
        *(bf16x8*)&vtl[(64+r2)*PK + s2*8] =
          *(const bf16x8*)&vt[((size_t)ch*80 + 64 + r2)*CL + s3*32 + s2*8];
    }
    __syncthreads();
    #pragma unroll
    for (int ss = 0; ss < 2; ++ss) {
      f32x4 dr = (f32x4){0.f,0.f,0.f,0.f};
      bf16x8 a0 = *(bf16x8*)&kgl[(ss*16+lm)*PQ + qq*8];
      bf16x8 a1 = *(bf16x8*)&kgl[(ss*16+lm)*PQ + 32 + qq*8];
      dr = MFMA(a0, bq0, dr);
      dr = MFMA(a1, bq1, dr);
      bf16x4 pk;
      #pragma unroll
      for (int j = 0; j < 4; ++j) {
        int s_g = s3*32 + ss*16 + qq*4 + j;
        float dv = dr[j];
        pk[j] = (__bf16)((s_g <= r_gc) ? dv*dv : 0.f);
      }
      *(bf16x4*)&As[(wv*16+lm)*PK + ss*16 + qq*4] = pk;
    }
    bf16x8 aav = *(bf16x8*)&As[(wv*16+lm)*PK + qq*8];
    #pragma unroll
    for (int n = 0; n < 5; ++n) {
      bf16x8 bv = *(bf16x8*)&vtl[(n*16+lm)*PK + qq*8];
      acc[n] = MFMA(aav, bv, acc[n]);
    }
  }
  if (c == 0) {
    #pragma unroll
    for (int j = 0; j < 4; ++j) {
      float rs = __shfl(acc[4][j], lane & 48, 64);
      float dinv = 1.f / fmaxf(rs, KEPS);
      int rg = rt*64 + wv*16 + qq*4 + j;
      size_t ob = ((size_t)(c*CL + rg)*NH + h)*ND + lm;
      #pragma unroll
      for (int n = 0; n < 4; ++n) out[ob + 16*n] = acc[n][j]*dinv;
    }
  } else {
    #pragma unroll
    for (int j = 0; j < 4; ++j) {
      int rg = rt*64 + wv*16 + qq*4 + j;
      size_t ob = ((size_t)(c*CL + rg)*NH + h)*ND + lm;
      #pragma unroll
      for (int n = 0; n < 4; ++n) out[ob + 16*n] = acc[n][j];
      if (lm == 0) rowp[ch*CL + rg] = acc[4][j];
    }
  }
}

// ---------------------------------------------------------------------------
// pzscan: fused P/Z compute + decay scan, chunks 0..2 sequential in-register.
// Block owns d in {2*mblk, 2*mblk+1} x e(64) x v(64 + ones col).
// P[(d,e)][v] = sum_l kh[l,d] kh[l,e] v[l,v]; S_reg = gt*S_reg + P.
// Writes bf16 st slab cc (S^T rows v=0..63, row 64 = sk) for chunk cc+1.
// ---------------------------------------------------------------------------
__global__ __launch_bounds__(256) void pzscan_kernel(const __bf16* __restrict__ kht,
    const __bf16* __restrict__ vt, const float* __restrict__ gtot,
    __bf16* __restrict__ st) {
  int mblk = blockIdx.x, h = blockIdx.y;
  int t = threadIdx.x, wv = t >> 6, lane = t & 63, qq = lane >> 4, lm = lane & 15;
  __shared__ __align__(16) __bf16 ke[64*PK];
  __shared__ __align__(16) __bf16 kd[2*PK];
  __shared__ __align__(16) __bf16 vtl[80*PK];
  __shared__ float tb[64][72];
  int dl = wv >> 1, e0w = (wv & 1)*32;
  f32x4 S_reg[2][5];
  #pragma unroll
  for (int m = 0; m < 2; ++m)
    #pragma unroll
    for (int n = 0; n < 5; ++n) S_reg[m][n] = (f32x4){0.f,0.f,0.f,0.f};
  for (int cc = 0; cc < 3; ++cc) {
    int ch = cc*NH + h;
    f32x4 acc[2][5];
    #pragma unroll
    for (int m = 0; m < 2; ++m)
      #pragma unroll
      for (int n = 0; n < 5; ++n) acc[m][n] = (f32x4){0.f,0.f,0.f,0.f};
    for (int kk = 0; kk < 32; ++kk) {
      int l0 = kk*32;
      __syncthreads();
      {
        int r = t >> 2, sg = t & 3;
        *(bf16x8*)&ke[r*PK + sg*8] =
          *(const bf16x8*)&kht[((size_t)ch*ND + r)*CL + l0 + sg*8];
        *(bf16x8*)&vtl[r*PK + sg*8] =
          *(const bf16x8*)&vt[((size_t)ch*80 + r)*CL + l0 + sg*8];
        if (t < 64)
          *(bf16x8*)&vtl[(64+r)*PK + sg*8] =
            *(const bf16x8*)&vt[((size_t)ch*80 + 64 + r)*CL + l0 + sg*8];
        if (t < 8)
          *(bf16x8*)&kd[(t>>2)*PK + (t&3)*8] =
            *(const bf16x8*)&kht[((size_t)ch*ND + mblk*2 + (t>>2))*CL + l0 + (t&3)*8];
      }
      __syncthreads();
      bf16x8 kd8 = *(bf16x8*)&kd[dl*PK + qq*8];
      bf16x8 am[2];
      #pragma unroll
      for (int m = 0; m < 2; ++m) {
        bf16x8 ke8 = *(bf16x8*)&ke[(e0w + 16*m + lm)*PK + qq*8];
        bf16x8 a;
        #pragma unroll
        for (int i = 0; i < 8; ++i) a[i] = (__bf16)((float)kd8[i] * (float)ke8[i]);
        am[m] = a;
      }
      #pragma unroll
      for (int n = 0; n < 5; ++n) {
        bf16x8 bv = *(bf16x8*)&vtl[(16*n+lm)*PK + qq*8];
        acc[0][n] = MFMA(am[0], bv, acc[0][n]);
        acc[1][n] = MFMA(am[1], bv, acc[1][n]);
      }
    }
    // decay-accumulate
    float gt = gtot[ch];
    #pragma unroll
    for (int m = 0; m < 2; ++m)
      #pragma unroll
      for (int n = 0; n < 5; ++n)
        #pragma unroll
        for (int j = 0; j < 4; ++j) S_reg[m][n][j] = gt*S_reg[m][n][j] + acc[m][n][j];
    // write st slab cc: rows v = S^T via LDS transpose (two d-halves), row 64 = sk
    size_t slab = (size_t)(cc*NH + h)*80;
    for (int h2 = 0; h2 < 2; ++h2) {
      __syncthreads();
      if (dl == h2) {
        #pragma unroll
        for (int m = 0; m < 2; ++m)
          #pragma unroll
          for (int n = 0; n < 4; ++n)
            #pragma unroll
            for (int j = 0; j < 4; ++j)
              tb[e0w + 16*m + qq*4 + j][16*n + lm] = S_reg[m][n][j];
      }
      __syncthreads();
      {
        int vr = t >> 2, es = t & 3;
        bf16x8 a, b;
        #pragma unroll
        for (int i = 0; i < 8; ++i) { a[i]=(__bf16)tb[es*16+i][vr]; b[i]=(__bf16)tb[es*16+8+i][vr]; }
        size_t sb = (slab + vr)*4096 + (size_t)(mblk*2 + h2)*64 + es*16;
        *(bf16x8*)&st[sb] = a; *(bf16x8*)&st[sb+8] = b;
      }
    }
    if (lm == 0) {
      #pragma unroll
      for (int m = 0; m < 2; ++m)
        #pragma unroll
        for (int j = 0; j < 4; ++j)
          st[(slab + 64)*4096 + (size_t)(mblk*2 + dl)*64 + e0w + 16*m + qq*4 + j] =
            (__bf16)S_reg[m][4][j];
    }
  }
}

// ---------------------------------------------------------------------------
// inter (chunks 1..3): out = (intra_num + phi(qg)@S) / max(row + phi.sk, eps)
// A-frag on the fly: a[e] = qg[r][d]*qg[r][e]. B = st rows (row64=sk -> den).
// ---------------------------------------------------------------------------
__global__ __launch_bounds__(256) void inter_kernel(const __bf16* __restrict__ qgb,
    const __bf16* __restrict__ st, const float* __restrict__ rowp, float* __restrict__ out) {
  int mb = blockIdx.x, h = blockIdx.y, c = blockIdx.z + 1;
  int ch = c*NH + h, slab = c - 1;
  int t = threadIdx.x, wv = t >> 6, lane = t & 63, qq = lane >> 4, lm = lane & 15;
  __shared__ __align__(16) __bf16 qt[64*PQ];
  __shared__ __align__(16) __bf16 stl[80*PK];
  {
    int r = t >> 2, sg = t & 3;
    size_t gb = ((size_t)ch*CL + mb*64 + r)*ND + sg*16;
    *(bf16x8*)&qt[r*PQ + sg*16]     = *(const bf16x8*)&qgb[gb];
    *(bf16x8*)&qt[r*PQ + sg*16 + 8] = *(const bf16x8*)&qgb[gb+8];
  }
  __syncthreads();
  f32x4 acc[5];
  #pragma unroll
  for (int n = 0; n < 5; ++n) acc[n] = (f32x4){0.f,0.f,0.f,0.f};
  int rrow = wv*16 + lm;
  for (int kk = 0; kk < 128; ++kk) {
    int d = kk >> 1, e0 = (kk & 1)*32;
    __syncthreads();
    {
      int r = t >> 2, sg = t & 3;
      *(bf16x8*)&stl[r*PK + sg*8] =
        *(const bf16x8*)&st[((size_t)(slab*NH+h)*80 + r)*4096 + kk*32 + sg*8];
      if (t < 4)
        *(bf16x8*)&stl[64*PK + t*8] =
          *(const bf16x8*)&st[((size_t)(slab*NH+h)*80 + 64)*4096 + kk*32 + t*8];
    }
    __syncthreads();
    float qd = (float)qt[rrow*PQ + d];
    bf16x8 qe = *(bf16x8*)&qt[rrow*PQ + e0 + qq*8];
    bf16x8 a;
    #pragma unroll
    for (int i = 0; i < 8; ++i) a[i] = (__bf16)(qd * (float)qe[i]);
    #pragma unroll
    for (int n = 0; n < 5; ++n) {
      bf16x8 bv = *(bf16x8*)&stl[(16*n+lm)*PK + qq*8];
      acc[n] = MFMA(a, bv, acc[n]);
    }
  }
  #pragma unroll
  for (int j = 0; j < 4; ++j) {
    float den = __shfl(acc[4][j], lane & 48, 64);
    int rg = mb*64 + wv*16 + qq*4 + j;
    float rv = rowp[ch*CL + rg];
    float dinv = 1.f / fmaxf(rv + den, KEPS);
    size_t ob = ((size_t)(c*CL + rg)*NH + h)*ND + lm;
    #pragma unroll
    for (int n = 0; n < 4; ++n) { size_t aoff = ob + 16*n; out[aoff] = (out[aoff] + acc[n][j]) * dinv; }
  }
}

// ---------------------------------------------------------------------------
extern "C" void kernel_launch(void* const* d_in, const int* in_sizes, int n_in,
                              void* d_out, int out_size, void* d_ws, size_t ws_size,
                              hipStream_t stream) {
  const float* q  = (const float*)d_in[0];
  const float* k  = (const float*)d_in[1];
  const float* v  = (const float*)d_in[2];
  const float* lg = (const float*)d_in[3];
  float* out = (float*)d_out;

  float* wf    = (float*)d_ws;
  float* g_arr = wf;                       // 32768 f32
  float* gend  = g_arr + 32768;            // 32
  float* gtot  = gend + 32;                // 32
  float* rowp  = gtot + 32;                // 32768
  __bf16* qgb  = (__bf16*)(rowp + 32768);  // 2,097,152 bf16 each
  __bf16* kgb  = qgb + 2097152;
  __bf16* kht  = kgb + 2097152;
  __bf16* vt   = kht + 2097152;            // 4*8*80*1024 = 2,621,440
  __bf16* st   = vt + 2621440;             // 3*8*80*4096 = 7,864,320
  // total ~33.8 MB

  gate_kernel<<<dim3(NC*NH), dim3(CL), 0, stream>>>(lg, g_arr, gend, gtot);
  convert_kernel<<<dim3(16, NH, NC), dim3(256), 0, stream>>>(q, k, v, g_arr, gend, qgb, kgb, kht, vt);
  intra_kernel<<<dim3(16, NH, NC), dim3(256), 0, stream>>>(qgb, kgb, vt, out, rowp);
  pzscan_kernel<<<dim3(32, NH), dim3(256), 0, stream>>>(kht, vt, gtot, st);
  inter_kernel<<<dim3(16, NH, 3), dim3(256), 0, stream>>>(qgb, st, rowp, out);
}

// Round 7
// 243.674 us; speedup vs baseline: 12.7874x; 1.1944x over previous
//
#include <hip/hip_runtime.h>
#include <math.h>

typedef float f32x4 __attribute__((ext_vector_type(4)));
typedef __bf16 bf16x8 __attribute__((ext_vector_type(8)));
typedef __bf16 bf16x4 __attribute__((ext_vector_type(4)));

namespace {
constexpr int NC = 4, CL = 1024, NH = 8, ND = 64;
constexpr float KSCALE = 0.125f, KEPS = 1e-6f;
constexpr int PQ = 72;   // LDS pitch (bf16) for [*][64] tiles: 144B rows, 16B-aligned
constexpr int PK = 40;   // LDS pitch (bf16) for [*][32] tiles: 80B rows, 16B-aligned
}

#define MFMA(a,b,c) __builtin_amdgcn_mfma_f32_16x16x32_bf16((a),(b),(c),0,0,0)

// ---------------------------------------------------------------------------
// gate: per (c,h) inclusive cumsum of log_g; write g, g_end, exp(g_end)
// ---------------------------------------------------------------------------
__global__ __launch_bounds__(1024) void gate_kernel(const float* __restrict__ lg,
    float* __restrict__ g_arr, float* __restrict__ gend, float* __restrict__ gtot) {
  int c = blockIdx.x >> 3, h = blockIdx.x & 7;
  int l = threadIdx.x;
  __shared__ float sm[CL];
  sm[l] = lg[(c*CL + l)*NH + h];
  __syncthreads();
  for (int off = 1; off < CL; off <<= 1) {
    float t = (l >= off) ? sm[l-off] : 0.f;
    __syncthreads();
    sm[l] += t;
    __syncthreads();
  }
  g_arr[(c*NH + h)*CL + l] = sm[l];
  if (l == 0) { gend[c*NH+h] = sm[CL-1]; gtot[c*NH+h] = expf(sm[CL-1]); }
}

// ---------------------------------------------------------------------------
// convert: bf16 operand arrays.
//   qgb[ch][l][d] = q*SCALE*exp(g/2)        (intra QK B-op, inter A-gen)
//   kgb[ch][l][d] = k*exp(-g/2)             (intra QK A-op)
//   kht[ch][d][l] = k*exp((gend-g)/2)       (pzscan A-gen, transposed)
//   vt [ch][p][l] p<64: v^T; p=64: ones; p=65..79: zeros  (B-op everywhere)
// ---------------------------------------------------------------------------
__global__ __launch_bounds__(256) void convert_kernel(const float* __restrict__ q,
    const float* __restrict__ k, const float* __restrict__ v,
    const float* __restrict__ g_arr, const float* __restrict__ gend,
    __bf16* __restrict__ qgb, __bf16* __restrict__ kgb,
    __bf16* __restrict__ kht, __bf16* __restrict__ vt) {
  int lt = blockIdx.x, h = blockIdx.y, c = blockIdx.z;
  int ch = c*NH + h;
  int t = threadIdx.x;
  __shared__ float ld[64][65];
  int lr = t >> 2, sg = t & 3;
  int l = lt*64 + lr;
  size_t ib = ((size_t)(c*CL + l)*NH + h)*ND + sg*16;
  float ge = gend[ch];
  float gl = g_arr[ch*CL + l];
  float eq = expf(0.5f*gl), ekk = expf(-0.5f*gl), ew = expf(0.5f*(ge-gl));
  float qv[16], kv[16], vv[16];
  #pragma unroll
  for (int i = 0; i < 4; ++i) {
    *(f32x4*)&qv[4*i] = *(const f32x4*)&q[ib+4*i];
    *(f32x4*)&kv[4*i] = *(const f32x4*)&k[ib+4*i];
    *(f32x4*)&vv[4*i] = *(const f32x4*)&v[ib+4*i];
  }
  size_t ob = ((size_t)ch*CL + l)*ND + sg*16;
  {
    bf16x8 a, b;
    #pragma unroll
    for (int i = 0; i < 8; ++i) { a[i]=(__bf16)(qv[i]*KSCALE*eq); b[i]=(__bf16)(qv[8+i]*KSCALE*eq); }
    *(bf16x8*)&qgb[ob] = a; *(bf16x8*)&qgb[ob+8] = b;
    #pragma unroll
    for (int i = 0; i < 8; ++i) { a[i]=(__bf16)(kv[i]*ekk); b[i]=(__bf16)(kv[8+i]*ekk); }
    *(bf16x8*)&kgb[ob] = a; *(bf16x8*)&kgb[ob+8] = b;
  }
  // kht transpose via LDS
  #pragma unroll
  for (int i = 0; i < 16; ++i) ld[lr][sg*16+i] = kv[i]*ew;
  __syncthreads();
  {
    int d = t >> 2, s2 = t & 3;
    bf16x8 a, b;
    #pragma unroll
    for (int i = 0; i < 8; ++i) { a[i]=(__bf16)ld[s2*16+i][d]; b[i]=(__bf16)ld[s2*16+8+i][d]; }
    size_t kb = ((size_t)ch*ND + d)*CL + lt*64 + s2*16;
    *(bf16x8*)&kht[kb] = a; *(bf16x8*)&kht[kb+8] = b;
  }
  __syncthreads();
  // vt transpose via LDS
  #pragma unroll
  for (int i = 0; i < 16; ++i) ld[lr][sg*16+i] = vv[i];
  __syncthreads();
  {
    int p = t >> 2, s2 = t & 3;
    bf16x8 a, b;
    #pragma unroll
    for (int i = 0; i < 8; ++i) { a[i]=(__bf16)ld[s2*16+i][p]; b[i]=(__bf16)ld[s2*16+8+i][p]; }
    size_t vb = ((size_t)ch*80 + p)*CL + lt*64 + s2*16;
    *(bf16x8*)&vt[vb] = a; *(bf16x8*)&vt[vb+8] = b;
  }
  if (t < 64) vt[((size_t)ch*80 + 64)*CL + lt*64 + t] = (__bf16)1.0f;
  for (int idx = t; idx < 15*64; idx += 256)
    vt[((size_t)ch*80 + 65 + idx/64)*CL + lt*64 + (idx & 63)] = (__bf16)0.0f;
}

// ---------------------------------------------------------------------------
// intra: causal. score=(qg.kg)^2 (gating prefolded). Swapped mfma(kg,qg)->S^T,
// square+mask, per-wave LDS bounce, A@V with vt (col64=rowsum).
// c==0: fuse divide (den_i=0). c>0: store raw num + row.
// ---------------------------------------------------------------------------
__global__ __launch_bounds__(256) void intra_kernel(const __bf16* __restrict__ qgb,
    const __bf16* __restrict__ kgb, const __bf16* __restrict__ vt,
    float* __restrict__ out, float* __restrict__ rowp) {
  int rt = blockIdx.x, h = blockIdx.y, c = blockIdx.z;
  int ch = c*NH + h;
  int t = threadIdx.x, wv = t >> 6, lane = t & 63, qq = lane >> 4, lm = lane & 15;
  __shared__ __align__(16) __bf16 qt[64*PQ];
  __shared__ __align__(16) __bf16 kgl[32*PQ];
  __shared__ __align__(16) __bf16 vtl[80*PK];
  __shared__ __align__(16) __bf16 As[64*PK];
  {
    int r = t >> 2, sg = t & 3;
    size_t gb = ((size_t)ch*CL + rt*64 + r)*ND + sg*16;
    *(bf16x8*)&qt[r*PQ + sg*16]     = *(const bf16x8*)&qgb[gb];
    *(bf16x8*)&qt[r*PQ + sg*16 + 8] = *(const bf16x8*)&qgb[gb+8];
  }
  __syncthreads();
  bf16x8 bq0 = *(bf16x8*)&qt[(wv*16+lm)*PQ + qq*8];
  bf16x8 bq1 = *(bf16x8*)&qt[(wv*16+lm)*PQ + 32 + qq*8];
  f32x4 acc[5];
  #pragma unroll
  for (int n = 0; n < 5; ++n) acc[n] = (f32x4){0.f,0.f,0.f,0.f};
  int r_gc = rt*64 + wv*16 + lm;
  int nst = 2*rt + 2;
  for (int s3 = 0; s3 < nst; ++s3) {
    __syncthreads();
    {
      int r = t >> 3, sg = t & 7;
      *(bf16x8*)&kgl[r*PQ + sg*8] =
        *(const bf16x8*)&kgb[((size_t)ch*CL + s3*32 + r)*ND + sg*8];
      int r2 = t >> 2, s2 = t & 3;
      *(bf16x8*)&vtl[r2*PK + s2*8] =
        *(const bf16x8*)&vt[((size_t)ch*80 + r2)*CL + s3*32 + s2*8];
      if (t < 64)
        *(bf16x8*)&vtl[(64+r2)*PK + s2*8] =
          *(const bf16x8*)&vt[((size_t)ch*80 + 64 + r2)*CL + s3*32 + s2*8];
    }
    __syncthreads();
    #pragma unroll
    for (int ss = 0; ss < 2; ++ss) {
      f32x4 dr = (f32x4){0.f,0.f,0.f,0.f};
      bf16x8 a0 = *(bf16x8*)&kgl[(ss*16+lm)*PQ + qq*8];
      bf16x8 a1 = *(bf16x8*)&kgl[(ss*16+lm)*PQ + 32 + qq*8];
      dr = MFMA(a0, bq0, dr);
      dr = MFMA(a1, bq1, dr);
      bf16x4 pk;
      #pragma unroll
      for (int j = 0; j < 4; ++j) {
        int s_g = s3*32 + ss*16 + qq*4 + j;
        float dv = dr[j];
        pk[j] = (__bf16)((s_g <= r_gc) ? dv*dv : 0.f);
      }
      *(bf16x4*)&As[(wv*16+lm)*PK + ss*16 + qq*4] = pk;
    }
    bf16x8 aav = *(bf16x8*)&As[(wv*16+lm)*PK + qq*8];
    #pragma unroll
    for (int n = 0; n < 5; ++n) {
      bf16x8 bv = *(bf16x8*)&vtl[(n*16+lm)*PK + qq*8];
      acc[n] = MFMA(aav, bv, acc[n]);
    }
  }
  if (c == 0) {
    #pragma unroll
    for (int j = 0; j < 4; ++j) {
      float rs = __shfl(acc[4][j], lane & 48, 64);
      float dinv = 1.f / fmaxf(rs, KEPS);
      int rg = rt*64 + wv*16 + qq*4 + j;
      size_t ob = ((size_t)(c*CL + rg)*NH + h)*ND + lm;
      #pragma unroll
      for (int n = 0; n < 4; ++n) out[ob + 16*n] = acc[n][j]*dinv;
    }
  } else {
    #pragma unroll
    for (int j = 0; j < 4; ++j) {
      int rg = rt*64 + wv*16 + qq*4 + j;
      size_t ob = ((size_t)(c*CL + rg)*NH + h)*ND + lm;
      #pragma unroll
      for (int n = 0; n < 4; ++n) out[ob + 16*n] = acc[n][j];
      if (lm == 0) rowp[ch*CL + rg] = acc[4][j];
    }
  }
}

// ---------------------------------------------------------------------------
// pzscan: fused P/Z compute + decay scan, chunks 0..2 sequential in-register.
// Block owns d in {2*mblk, 2*mblk+1} x e(64) x v(64 + ones col).
// P[(d,e)][v] = sum_l kh[l,d] kh[l,e] v[l,v]; S_reg = gt*S_reg + P.
// Writes bf16 st slab cc (S^T rows v=0..63, row 64 = sk) for chunk cc+1.
// ---------------------------------------------------------------------------
__global__ __launch_bounds__(256) void pzscan_kernel(const __bf16* __restrict__ kht,
    const __bf16* __restrict__ vt, const float* __restrict__ gtot,
    __bf16* __restrict__ st) {
  int mblk = blockIdx.x, h = blockIdx.y;
  int t = threadIdx.x, wv = t >> 6, lane = t & 63, qq = lane >> 4, lm = lane & 15;
  __shared__ __align__(16) __bf16 ke[64*PK];
  __shared__ __align__(16) __bf16 kd[2*PK];
  __shared__ __align__(16) __bf16 vtl[80*PK];
  __shared__ float tb[64][72];
  int dl = wv >> 1, e0w = (wv & 1)*32;
  f32x4 S_reg[2][5];
  #pragma unroll
  for (int m = 0; m < 2; ++m)
    #pragma unroll
    for (int n = 0; n < 5; ++n) S_reg[m][n] = (f32x4){0.f,0.f,0.f,0.f};
  for (int cc = 0; cc < 3; ++cc) {
    int ch = cc*NH + h;
    f32x4 acc[2][5];
    #pragma unroll
    for (int m = 0; m < 2; ++m)
      #pragma unroll
      for (int n = 0; n < 5; ++n) acc[m][n] = (f32x4){0.f,0.f,0.f,0.f};
    for (int kk = 0; kk < 32; ++kk) {
      int l0 = kk*32;
      __syncthreads();
      {
        int r = t >> 2, sg = t & 3;
        *(bf16x8*)&ke[r*PK + sg*8] =
          *(const bf16x8*)&kht[((size_t)ch*ND + r)*CL + l0 + sg*8];
        *(bf16x8*)&vtl[r*PK + sg*8] =
          *(const bf16x8*)&vt[((size_t)ch*80 + r)*CL + l0 + sg*8];
        if (t < 64)
          *(bf16x8*)&vtl[(64+r)*PK + sg*8] =
            *(const bf16x8*)&vt[((size_t)ch*80 + 64 + r)*CL + l0 + sg*8];
        if (t < 8)
          *(bf16x8*)&kd[(t>>2)*PK + (t&3)*8] =
            *(const bf16x8*)&kht[((size_t)ch*ND + mblk*2 + (t>>2))*CL + l0 + (t&3)*8];
      }
      __syncthreads();
      bf16x8 kd8 = *(bf16x8*)&kd[dl*PK + qq*8];
      bf16x8 am[2];
      #pragma unroll
      for (int m = 0; m < 2; ++m) {
        bf16x8 ke8 = *(bf16x8*)&ke[(e0w + 16*m + lm)*PK + qq*8];
        bf16x8 a;
        #pragma unroll
        for (int i = 0; i < 8; ++i) a[i] = (__bf16)((float)kd8[i] * (float)ke8[i]);
        am[m] = a;
      }
      #pragma unroll
      for (int n = 0; n < 5; ++n) {
        bf16x8 bv = *(bf16x8*)&vtl[(16*n+lm)*PK + qq*8];
        acc[0][n] = MFMA(am[0], bv, acc[0][n]);
        acc[1][n] = MFMA(am[1], bv, acc[1][n]);
      }
    }
    // decay-accumulate
    float gt = gtot[ch];
    #pragma unroll
    for (int m = 0; m < 2; ++m)
      #pragma unroll
      for (int n = 0; n < 5; ++n)
        #pragma unroll
        for (int j = 0; j < 4; ++j) S_reg[m][n][j] = gt*S_reg[m][n][j] + acc[m][n][j];
    // write st slab cc: rows v = S^T via LDS transpose (two d-halves), row 64 = sk
    size_t slab = (size_t)(cc*NH + h)*80;
    for (int h2 = 0; h2 < 2; ++h2) {
      __syncthreads();
      if (dl == h2) {
        #pragma unroll
        for (int m = 0; m < 2; ++m)
          #pragma unroll
          for (int n = 0; n < 4; ++n)
            #pragma unroll
            for (int j = 0; j < 4; ++j)
              tb[e0w + 16*m + qq*4 + j][16*n + lm] = S_reg[m][n][j];
      }
      __syncthreads();
      {
        int vr = t >> 2, es = t & 3;
        bf16x8 a, b;
        #pragma unroll
        for (int i = 0; i < 8; ++i) { a[i]=(__bf16)tb[es*16+i][vr]; b[i]=(__bf16)tb[es*16+8+i][vr]; }
        size_t sb = (slab + vr)*4096 + (size_t)(mblk*2 + h2)*64 + es*16;
        *(bf16x8*)&st[sb] = a; *(bf16x8*)&st[sb+8] = b;
      }
    }
    if (lm == 0) {
      #pragma unroll
      for (int m = 0; m < 2; ++m)
        #pragma unroll
        for (int j = 0; j < 4; ++j)
          st[(slab + 64)*4096 + (size_t)(mblk*2 + dl)*64 + e0w + 16*m + qq*4 + j] =
            (__bf16)S_reg[m][4][j];
    }
  }
}

// ---------------------------------------------------------------------------
// inter_partial (chunks 1..3, K split 4-way): partial phi(qg)@S into pnum/pden
// via f32 atomics. Per block: 64 q-rows x 65 cols x 16 d-phases (K=1024).
// Single-barrier double-buffered LDS pipeline; A-gen inputs all in registers.
// ---------------------------------------------------------------------------
__global__ __launch_bounds__(256) void inter_partial_kernel(
    const __bf16* __restrict__ qgb, const __bf16* __restrict__ st,
    float* __restrict__ pnum, float* __restrict__ pden) {
  int mb = blockIdx.x;          // 0..15 : 64-row tile
  int ks = blockIdx.y;          // 0..3  : K quarter (16 d values)
  int hc = blockIdx.z;          // 0..23 : slab*8 + h
  int slab = hc >> 3, h = hc & 7;
  int c = slab + 1, ch = c*NH + h;
  int t = threadIdx.x, wv = t >> 6, lane = t & 63, qq = lane >> 4, lm = lane & 15;
  __shared__ __align__(16) __bf16 stl[2][65*PQ];
  size_t slabbase = (size_t)(slab*NH + h)*80;
  // per-lane q-row operands, hoisted once (e-range identical every phase)
  int rrow = mb*64 + wv*16 + lm;
  size_t qb = ((size_t)ch*CL + rrow)*ND;
  bf16x8 qe0 = *(const bf16x8*)&qgb[qb + qq*8];
  bf16x8 qe1 = *(const bf16x8*)&qgb[qb + 32 + qq*8];
  float qd[16];
  {
    bf16x8 qa = *(const bf16x8*)&qgb[qb + ks*16];
    bf16x8 qbv = *(const bf16x8*)&qgb[qb + ks*16 + 8];
    #pragma unroll
    for (int i = 0; i < 8; ++i) { qd[i] = (float)qa[i]; qd[8+i] = (float)qbv[i]; }
  }
  int r = t >> 2, cg = t & 3;
  bf16x8 sa, sb, sc;
  auto load_ph = [&](int ph) {
    size_t base = (slabbase + r)*4096 + (size_t)(ks*16 + ph)*64 + cg*16;
    sa = *(const bf16x8*)&st[base];
    sb = *(const bf16x8*)&st[base + 8];
    if (t < 8) sc = *(const bf16x8*)&st[(slabbase + 64)*4096 + (size_t)(ks*16 + ph)*64 + t*8];
  };
  auto write_ph = [&](int buf) {
    *(bf16x8*)&stl[buf][r*PQ + cg*16]     = sa;
    *(bf16x8*)&stl[buf][r*PQ + cg*16 + 8] = sb;
    if (t < 8) *(bf16x8*)&stl[buf][64*PQ + t*8] = sc;
  };
  f32x4 acc[5];
  #pragma unroll
  for (int n = 0; n < 5; ++n) acc[n] = (f32x4){0.f,0.f,0.f,0.f};
  load_ph(0);
  write_ph(0);
  __syncthreads();
  #pragma unroll
  for (int ph = 0; ph < 16; ++ph) {
    int buf = ph & 1;
    if (ph < 15) load_ph(ph + 1);          // issue next-phase loads early
    float qdv = qd[ph];
    #pragma unroll
    for (int s = 0; s < 2; ++s) {
      bf16x8 qe = s ? qe1 : qe0;
      bf16x8 a;
      #pragma unroll
      for (int i = 0; i < 8; ++i) a[i] = (__bf16)(qdv * (float)qe[i]);
      #pragma unroll
      for (int n = 0; n < 5; ++n) {
        bf16x8 bv = *(bf16x8*)&stl[buf][(16*n + lm)*PQ + s*32 + qq*8];
        acc[n] = MFMA(a, bv, acc[n]);
      }
    }
    if (ph < 15) write_ph(buf ^ 1);        // write-late (after compute)
    __syncthreads();
  }
  size_t prow = (size_t)hc*1024 + mb*64 + wv*16;
  #pragma unroll
  for (int j = 0; j < 4; ++j) {
    int rloc = qq*4 + j;
    #pragma unroll
    for (int n = 0; n < 4; ++n)
      atomicAdd(&pnum[(prow + rloc)*64 + 16*n + lm], acc[n][j]);
    if (lm == 0) atomicAdd(&pden[prow + rloc], acc[4][j]);
  }
}

// ---------------------------------------------------------------------------
// finalize (chunks 1..3): out = (intra_num + pnum) / max(row + pden, eps)
// ---------------------------------------------------------------------------
__global__ __launch_bounds__(256) void finalize_kernel(const float* __restrict__ rowp,
    const float* __restrict__ pnum, const float* __restrict__ pden,
    float* __restrict__ out) {
  int idx = blockIdx.x*256 + threadIdx.x;
  int e4 = idx*4;
  int row = e4 >> 6;                  // hc*1024 + rg
  int col = e4 & 63;
  int hc = row >> 10, rg = row & 1023;
  int slab = hc >> 3, h = hc & 7, c = slab + 1;
  float dinv = 1.f / fmaxf(rowp[(c*NH + h)*CL + rg] + pden[row], KEPS);
  f32x4 pv = *(const f32x4*)&pnum[e4];
  size_t ob = ((size_t)(c*CL + rg)*NH + h)*ND + col;
  f32x4 ov = *(const f32x4*)&out[ob];
  #pragma unroll
  for (int j = 0; j < 4; ++j) ov[j] = (ov[j] + pv[j]) * dinv;
  *(f32x4*)&out[ob] = ov;
}

// ---------------------------------------------------------------------------
extern "C" void kernel_launch(void* const* d_in, const int* in_sizes, int n_in,
                              void* d_out, int out_size, void* d_ws, size_t ws_size,
                              hipStream_t stream) {
  const float* q  = (const float*)d_in[0];
  const float* k  = (const float*)d_in[1];
  const float* v  = (const float*)d_in[2];
  const float* lg = (const float*)d_in[3];
  float* out = (float*)d_out;

  float* wf    = (float*)d_ws;
  float* g_arr = wf;                       // 32768 f32
  float* gend  = g_arr + 32768;            // 32
  float* gtot  = gend + 32;                // 32
  float* rowp  = gtot + 32;                // 32768
  float* pden  = rowp + 32768;             // 24576
  float* pnum  = pden + 24576;             // 1,572,864
  __bf16* qgb  = (__bf16*)(pnum + 1572864);// 2,097,152 bf16 each
  __bf16* kgb  = qgb + 2097152;
  __bf16* kht  = kgb + 2097152;
  __bf16* vt   = kht + 2097152;            // 4*8*80*1024 = 2,621,440
  __bf16* st   = vt + 2621440;             // 3*8*80*4096 = 7,864,320
  // total ~40.2 MB

  hipMemsetAsync(pden, 0, (size_t)(24576 + 1572864)*sizeof(float), stream);
  gate_kernel<<<dim3(NC*NH), dim3(CL), 0, stream>>>(lg, g_arr, gend, gtot);
  convert_kernel<<<dim3(16, NH, NC), dim3(256), 0, stream>>>(q, k, v, g_arr, gend, qgb, kgb, kht, vt);
  intra_kernel<<<dim3(16, NH, NC), dim3(256), 0, stream>>>(qgb, kgb, vt, out, rowp);
  pzscan_kernel<<<dim3(32, NH), dim3(256), 0, stream>>>(kht, vt, gtot, st);
  inter_partial_kernel<<<dim3(16, 4, 24), dim3(256), 0, stream>>>(qgb, st, pnum, pden);
  finalize_kernel<<<dim3(1536), dim3(256), 0, stream>>>(rowp, pnum, pden, out);
}

// Round 8
// 215.574 us; speedup vs baseline: 14.4543x; 1.1303x over previous
//
#include <hip/hip_runtime.h>
#include <math.h>

typedef float f32x4 __attribute__((ext_vector_type(4)));
typedef __bf16 bf16x8 __attribute__((ext_vector_type(8)));
typedef __bf16 bf16x4 __attribute__((ext_vector_type(4)));

namespace {
constexpr int NC = 4, CL = 1024, NH = 8, ND = 64;
constexpr float KSCALE = 0.125f, KEPS = 1e-6f;
constexpr int PQ = 72;   // LDS pitch (bf16) for [*][64] tiles: 144B rows, 16B-aligned
constexpr int PK = 40;   // LDS pitch (bf16) for [*][32] tiles: 80B rows, 16B-aligned
}

#define MFMA(a,b,c) __builtin_amdgcn_mfma_f32_16x16x32_bf16((a),(b),(c),0,0,0)

// ---------------------------------------------------------------------------
// gate: per (c,h) inclusive cumsum of log_g; write g, g_end, exp(g_end)
// ---------------------------------------------------------------------------
__global__ __launch_bounds__(1024) void gate_kernel(const float* __restrict__ lg,
    float* __restrict__ g_arr, float* __restrict__ gend, float* __restrict__ gtot) {
  int c = blockIdx.x >> 3, h = blockIdx.x & 7;
  int l = threadIdx.x;
  __shared__ float sm[CL];
  sm[l] = lg[(c*CL + l)*NH + h];
  __syncthreads();
  for (int off = 1; off < CL; off <<= 1) {
    float t = (l >= off) ? sm[l-off] : 0.f;
    __syncthreads();
    sm[l] += t;
    __syncthreads();
  }
  g_arr[(c*NH + h)*CL + l] = sm[l];
  if (l == 0) { gend[c*NH+h] = sm[CL-1]; gtot[c*NH+h] = expf(sm[CL-1]); }
}

// ---------------------------------------------------------------------------
// convert: bf16 operand arrays.
//   qgb[ch][l][d] = q*SCALE*exp(g/2)        (intra QK B-op, inter A-gen)
//   kgb[ch][l][d] = k*exp(-g/2)             (intra QK A-op)
//   kht[ch][d][l] = k*exp((gend-g)/2)       (pzscan A-gen, transposed)
//   vt [ch][p][l] p<64: v^T; p=64: ones; p=65..79: zeros  (B-op everywhere)
// ---------------------------------------------------------------------------
__global__ __launch_bounds__(256) void convert_kernel(const float* __restrict__ q,
    const float* __restrict__ k, const float* __restrict__ v,
    const float* __restrict__ g_arr, const float* __restrict__ gend,
    __bf16* __restrict__ qgb, __bf16* __restrict__ kgb,
    __bf16* __restrict__ kht, __bf16* __restrict__ vt) {
  int lt = blockIdx.x, h = blockIdx.y, c = blockIdx.z;
  int ch = c*NH + h;
  int t = threadIdx.x;
  __shared__ float ld[64][65];
  int lr = t >> 2, sg = t & 3;
  int l = lt*64 + lr;
  size_t ib = ((size_t)(c*CL + l)*NH + h)*ND + sg*16;
  float ge = gend[ch];
  float gl = g_arr[ch*CL + l];
  float eq = expf(0.5f*gl), ekk = expf(-0.5f*gl), ew = expf(0.5f*(ge-gl));
  float qv[16], kv[16], vv[16];
  #pragma unroll
  for (int i = 0; i < 4; ++i) {
    *(f32x4*)&qv[4*i] = *(const f32x4*)&q[ib+4*i];
    *(f32x4*)&kv[4*i] = *(const f32x4*)&k[ib+4*i];
    *(f32x4*)&vv[4*i] = *(const f32x4*)&v[ib+4*i];
  }
  size_t ob = ((size_t)ch*CL + l)*ND + sg*16;
  {
    bf16x8 a, b;
    #pragma unroll
    for (int i = 0; i < 8; ++i) { a[i]=(__bf16)(qv[i]*KSCALE*eq); b[i]=(__bf16)(qv[8+i]*KSCALE*eq); }
    *(bf16x8*)&qgb[ob] = a; *(bf16x8*)&qgb[ob+8] = b;
    #pragma unroll
    for (int i = 0; i < 8; ++i) { a[i]=(__bf16)(kv[i]*ekk); b[i]=(__bf16)(kv[8+i]*ekk); }
    *(bf16x8*)&kgb[ob] = a; *(bf16x8*)&kgb[ob+8] = b;
  }
  // kht transpose via LDS
  #pragma unroll
  for (int i = 0; i < 16; ++i) ld[lr][sg*16+i] = kv[i]*ew;
  __syncthreads();
  {
    int d = t >> 2, s2 = t & 3;
    bf16x8 a, b;
    #pragma unroll
    for (int i = 0; i < 8; ++i) { a[i]=(__bf16)ld[s2*16+i][d]; b[i]=(__bf16)ld[s2*16+8+i][d]; }
    size_t kb = ((size_t)ch*ND + d)*CL + lt*64 + s2*16;
    *(bf16x8*)&kht[kb] = a; *(bf16x8*)&kht[kb+8] = b;
  }
  __syncthreads();
  // vt transpose via LDS
  #pragma unroll
  for (int i = 0; i < 16; ++i) ld[lr][sg*16+i] = vv[i];
  __syncthreads();
  {
    int p = t >> 2, s2 = t & 3;
    bf16x8 a, b;
    #pragma unroll
    for (int i = 0; i < 8; ++i) { a[i]=(__bf16)ld[s2*16+i][p]; b[i]=(__bf16)ld[s2*16+8+i][p]; }
    size_t vb = ((size_t)ch*80 + p)*CL + lt*64 + s2*16;
    *(bf16x8*)&vt[vb] = a; *(bf16x8*)&vt[vb+8] = b;
  }
  if (t < 64) vt[((size_t)ch*80 + 64)*CL + lt*64 + t] = (__bf16)1.0f;
  for (int idx = t; idx < 15*64; idx += 256)
    vt[((size_t)ch*80 + 65 + idx/64)*CL + lt*64 + (idx & 63)] = (__bf16)0.0f;
}

// ---------------------------------------------------------------------------
// intra v2: causal, single-barrier double-buffered pipeline.
// score=(qg.kg)^2 (gating prefolded). Swapped mfma(kg,qg), square+mask,
// per-wave As bounce (no barrier needed), A@V with vt (col64=rowsum).
// ---------------------------------------------------------------------------
__global__ __launch_bounds__(256) void intra_kernel(const __bf16* __restrict__ qgb,
    const __bf16* __restrict__ kgb, const __bf16* __restrict__ vt,
    float* __restrict__ out, float* __restrict__ rowp) {
  int rt = blockIdx.x, h = blockIdx.y, c = blockIdx.z;
  int ch = c*NH + h;
  int t = threadIdx.x, wv = t >> 6, lane = t & 63, qq = lane >> 4, lm = lane & 15;
  __shared__ __align__(16) __bf16 qt[64*PQ];
  __shared__ __align__(16) __bf16 kgl[2][32*PQ];
  __shared__ __align__(16) __bf16 vtl[2][80*PK];
  __shared__ __align__(16) __bf16 As[64*PK];
  int nst = 2*rt + 2;
  // staging coords
  int r8 = t >> 3, sg8 = t & 7;   // kgl: 32 rows x 64 cols
  int r4 = t >> 2, s4 = t & 3;    // vtl: 80 rows x 32 cols
  bf16x8 rkg, rva, rvb;
  auto load_it = [&](int s3) {
    rkg = *(const bf16x8*)&kgb[((size_t)ch*CL + s3*32 + r8)*ND + sg8*8];
    rva = *(const bf16x8*)&vt[((size_t)ch*80 + r4)*CL + s3*32 + s4*8];
    if (t < 64) rvb = *(const bf16x8*)&vt[((size_t)ch*80 + 64 + r4)*CL + s3*32 + s4*8];
  };
  auto write_it = [&](int buf) {
    *(bf16x8*)&kgl[buf][r8*PQ + sg8*8] = rkg;
    *(bf16x8*)&vtl[buf][r4*PK + s4*8] = rva;
    if (t < 64) *(bf16x8*)&vtl[buf][(64+r4)*PK + s4*8] = rvb;
  };
  {
    int r = t >> 2, sg = t & 3;
    size_t gb = ((size_t)ch*CL + rt*64 + r)*ND + sg*16;
    *(bf16x8*)&qt[r*PQ + sg*16]     = *(const bf16x8*)&qgb[gb];
    *(bf16x8*)&qt[r*PQ + sg*16 + 8] = *(const bf16x8*)&qgb[gb+8];
  }
  load_it(0);
  write_it(0);
  __syncthreads();
  bf16x8 bq0 = *(bf16x8*)&qt[(wv*16+lm)*PQ + qq*8];
  bf16x8 bq1 = *(bf16x8*)&qt[(wv*16+lm)*PQ + 32 + qq*8];
  f32x4 acc[5];
  #pragma unroll
  for (int n = 0; n < 5; ++n) acc[n] = (f32x4){0.f,0.f,0.f,0.f};
  int r_gc = rt*64 + wv*16 + lm;
  int buf = 0;
  for (int s3 = 0; s3 < nst; ++s3) {
    if (s3 + 1 < nst) load_it(s3 + 1);          // issue next-tile loads early
    #pragma unroll
    for (int ss = 0; ss < 2; ++ss) {
      f32x4 dr = (f32x4){0.f,0.f,0.f,0.f};
      bf16x8 a0 = *(bf16x8*)&kgl[buf][(ss*16+lm)*PQ + qq*8];
      bf16x8 a1 = *(bf16x8*)&kgl[buf][(ss*16+lm)*PQ + 32 + qq*8];
      dr = MFMA(a0, bq0, dr);
      dr = MFMA(a1, bq1, dr);
      bf16x4 pk;
      #pragma unroll
      for (int j = 0; j < 4; ++j) {
        int s_g = s3*32 + ss*16 + qq*4 + j;
        float dv = dr[j];
        pk[j] = (__bf16)((s_g <= r_gc) ? dv*dv : 0.f);
      }
      *(bf16x4*)&As[(wv*16+lm)*PK + ss*16 + qq*4] = pk;
    }
    bf16x8 aav = *(bf16x8*)&As[(wv*16+lm)*PK + qq*8];
    #pragma unroll
    for (int n = 0; n < 5; ++n) {
      bf16x8 bv = *(bf16x8*)&vtl[buf][(n*16+lm)*PK + qq*8];
      acc[n] = MFMA(aav, bv, acc[n]);
    }
    if (s3 + 1 < nst) write_it(buf ^ 1);        // write-late
    __syncthreads();
    buf ^= 1;
  }
  if (c == 0) {
    #pragma unroll
    for (int j = 0; j < 4; ++j) {
      float rs = __shfl(acc[4][j], lane & 48, 64);
      float dinv = 1.f / fmaxf(rs, KEPS);
      int rg = rt*64 + wv*16 + qq*4 + j;
      size_t ob = ((size_t)(c*CL + rg)*NH + h)*ND + lm;
      #pragma unroll
      for (int n = 0; n < 4; ++n) out[ob + 16*n] = acc[n][j]*dinv;
    }
  } else {
    #pragma unroll
    for (int j = 0; j < 4; ++j) {
      int rg = rt*64 + wv*16 + qq*4 + j;
      size_t ob = ((size_t)(c*CL + rg)*NH + h)*ND + lm;
      #pragma unroll
      for (int n = 0; n < 4; ++n) out[ob + 16*n] = acc[n][j];
      if (lm == 0) rowp[ch*CL + rg] = acc[4][j];
    }
  }
}

// ---------------------------------------------------------------------------
// pzscan v2: fused P/Z + decay scan, flattened 96-iter single-barrier
// double-buffered pipeline. Block owns d-pair x e(64) x v(64 + ones col).
// P[(d,e)][v] = sum_l kh[l,d] kh[l,e] v[l,v]; S_reg = gt*S_reg + P per chunk.
// Writes bf16 st slab cc (S^T rows v=0..63, row 64 = sk) for chunk cc+1.
// ---------------------------------------------------------------------------
__global__ __launch_bounds__(256) void pzscan_kernel(const __bf16* __restrict__ kht,
    const __bf16* __restrict__ vt, const float* __restrict__ gtot,
    __bf16* __restrict__ st) {
  int mblk = blockIdx.x, h = blockIdx.y;
  int t = threadIdx.x, wv = t >> 6, lane = t & 63, qq = lane >> 4, lm = lane & 15;
  __shared__ __align__(16) __bf16 ke[2][64*PK];
  __shared__ __align__(16) __bf16 kd[2][2*PK];
  __shared__ __align__(16) __bf16 vtl[2][80*PK];
  __shared__ float tb[64][72];
  int dl = wv >> 1, e0w = (wv & 1)*32;
  int r = t >> 2, cg = t & 3;
  bf16x8 rke, rva, rvb, rkd;
  auto load_it = [&](int it) {
    int cc = it >> 5, kk = it & 31;
    int ch = cc*NH + h;
    int l0 = kk*32;
    rke = *(const bf16x8*)&kht[((size_t)ch*ND + r)*CL + l0 + cg*8];
    rva = *(const bf16x8*)&vt[((size_t)ch*80 + r)*CL + l0 + cg*8];
    if (t < 64) rvb = *(const bf16x8*)&vt[((size_t)ch*80 + 64 + r)*CL + l0 + cg*8];
    if (t < 8)  rkd = *(const bf16x8*)&kht[((size_t)ch*ND + mblk*2 + (t>>2))*CL + l0 + (t&3)*8];
  };
  auto write_it = [&](int buf) {
    *(bf16x8*)&ke[buf][r*PK + cg*8] = rke;
    *(bf16x8*)&vtl[buf][r*PK + cg*8] = rva;
    if (t < 64) *(bf16x8*)&vtl[buf][(64+r)*PK + cg*8] = rvb;
    if (t < 8)  *(bf16x8*)&kd[buf][(t>>2)*PK + (t&3)*8] = rkd;
  };
  f32x4 S_reg[2][5], acc[2][5];
  #pragma unroll
  for (int m = 0; m < 2; ++m)
    #pragma unroll
    for (int n = 0; n < 5; ++n) {
      S_reg[m][n] = (f32x4){0.f,0.f,0.f,0.f};
      acc[m][n] = (f32x4){0.f,0.f,0.f,0.f};
    }
  load_it(0);
  write_it(0);
  __syncthreads();
  int buf = 0;
  for (int it = 0; it < 96; ++it) {
    if (it < 95) load_it(it + 1);          // issue next-tile loads early
    bf16x8 kd8 = *(bf16x8*)&kd[buf][dl*PK + qq*8];
    bf16x8 am[2];
    #pragma unroll
    for (int m = 0; m < 2; ++m) {
      bf16x8 ke8 = *(bf16x8*)&ke[buf][(e0w + 16*m + lm)*PK + qq*8];
      bf16x8 a;
      #pragma unroll
      for (int i = 0; i < 8; ++i) a[i] = (__bf16)((float)kd8[i] * (float)ke8[i]);
      am[m] = a;
    }
    #pragma unroll
    for (int n = 0; n < 5; ++n) {
      bf16x8 bv = *(bf16x8*)&vtl[buf][(16*n+lm)*PK + qq*8];
      acc[0][n] = MFMA(am[0], bv, acc[0][n]);
      acc[1][n] = MFMA(am[1], bv, acc[1][n]);
    }
    if (it < 95) write_it(buf ^ 1);        // write-late
    __syncthreads();
    buf ^= 1;
    if ((it & 31) == 31) {
      int cc = it >> 5;
      // decay-accumulate, reset per-chunk acc
      float gt = gtot[cc*NH + h];
      #pragma unroll
      for (int m = 0; m < 2; ++m)
        #pragma unroll
        for (int n = 0; n < 5; ++n)
          #pragma unroll
          for (int j = 0; j < 4; ++j) {
            S_reg[m][n][j] = gt*S_reg[m][n][j] + acc[m][n][j];
            acc[m][n][j] = 0.f;
          }
      // write st slab cc: rows v = S^T via tb transpose (2 d-halves), row64 = sk
      size_t slab = (size_t)(cc*NH + h)*80;
      for (int h2 = 0; h2 < 2; ++h2) {
        __syncthreads();
        if (dl == h2) {
          #pragma unroll
          for (int m = 0; m < 2; ++m)
            #pragma unroll
            for (int n = 0; n < 4; ++n)
              #pragma unroll
              for (int j = 0; j < 4; ++j)
                tb[e0w + 16*m + qq*4 + j][16*n + lm] = S_reg[m][n][j];
        }
        __syncthreads();
        {
          int vr = t >> 2, es = t & 3;
          bf16x8 a, b;
          #pragma unroll
          for (int i = 0; i < 8; ++i) { a[i]=(__bf16)tb[es*16+i][vr]; b[i]=(__bf16)tb[es*16+8+i][vr]; }
          size_t sb = (slab + vr)*4096 + (size_t)(mblk*2 + h2)*64 + es*16;
          *(bf16x8*)&st[sb] = a; *(bf16x8*)&st[sb+8] = b;
        }
      }
      if (lm == 0) {
        #pragma unroll
        for (int m = 0; m < 2; ++m)
          #pragma unroll
          for (int j = 0; j < 4; ++j)
            st[(slab + 64)*4096 + (size_t)(mblk*2 + dl)*64 + e0w + 16*m + qq*4 + j] =
              (__bf16)S_reg[m][4][j];
      }
    }
  }
}

// ---------------------------------------------------------------------------
// inter_partial (chunks 1..3, K split 4-way): partial phi(qg)@S into pnum/pden
// via f32 atomics. Per block: 64 q-rows x 65 cols x 16 d-phases (K=1024).
// Single-barrier double-buffered LDS pipeline; A-gen inputs all in registers.
// ---------------------------------------------------------------------------
__global__ __launch_bounds__(256) void inter_partial_kernel(
    const __bf16* __restrict__ qgb, const __bf16* __restrict__ st,
    float* __restrict__ pnum, float* __restrict__ pden) {
  int mb = blockIdx.x;          // 0..15 : 64-row tile
  int ks = blockIdx.y;          // 0..3  : K quarter (16 d values)
  int hc = blockIdx.z;          // 0..23 : slab*8 + h
  int slab = hc >> 3, h = hc & 7;
  int c = slab + 1, ch = c*NH + h;
  int t = threadIdx.x, wv = t >> 6, lane = t & 63, qq = lane >> 4, lm = lane & 15;
  __shared__ __align__(16) __bf16 stl[2][65*PQ];
  size_t slabbase = (size_t)(slab*NH + h)*80;
  // per-lane q-row operands, hoisted once (e-range identical every phase)
  int rrow = mb*64 + wv*16 + lm;
  size_t qb = ((size_t)ch*CL + rrow)*ND;
  bf16x8 qe0 = *(const bf16x8*)&qgb[qb + qq*8];
  bf16x8 qe1 = *(const bf16x8*)&qgb[qb + 32 + qq*8];
  float qd[16];
  {
    bf16x8 qa = *(const bf16x8*)&qgb[qb + ks*16];
    bf16x8 qbv = *(const bf16x8*)&qgb[qb + ks*16 + 8];
    #pragma unroll
    for (int i = 0; i < 8; ++i) { qd[i] = (float)qa[i]; qd[8+i] = (float)qbv[i]; }
  }
  int r = t >> 2, cg = t & 3;
  bf16x8 sa, sb, sc;
  auto load_ph = [&](int ph) {
    size_t base = (slabbase + r)*4096 + (size_t)(ks*16 + ph)*64 + cg*16;
    sa = *(const bf16x8*)&st[base];
    sb = *(const bf16x8*)&st[base + 8];
    if (t < 8) sc = *(const bf16x8*)&st[(slabbase + 64)*4096 + (size_t)(ks*16 + ph)*64 + t*8];
  };
  auto write_ph = [&](int buf) {
    *(bf16x8*)&stl[buf][r*PQ + cg*16]     = sa;
    *(bf16x8*)&stl[buf][r*PQ + cg*16 + 8] = sb;
    if (t < 8) *(bf16x8*)&stl[buf][64*PQ + t*8] = sc;
  };
  f32x4 acc[5];
  #pragma unroll
  for (int n = 0; n < 5; ++n) acc[n] = (f32x4){0.f,0.f,0.f,0.f};
  load_ph(0);
  write_ph(0);
  __syncthreads();
  #pragma unroll
  for (int ph = 0; ph < 16; ++ph) {
    int buf = ph & 1;
    if (ph < 15) load_ph(ph + 1);          // issue next-phase loads early
    float qdv = qd[ph];
    #pragma unroll
    for (int s = 0; s < 2; ++s) {
      bf16x8 qe = s ? qe1 : qe0;
      bf16x8 a;
      #pragma unroll
      for (int i = 0; i < 8; ++i) a[i] = (__bf16)(qdv * (float)qe[i]);
      #pragma unroll
      for (int n = 0; n < 5; ++n) {
        bf16x8 bv = *(bf16x8*)&stl[buf][(16*n + lm)*PQ + s*32 + qq*8];
        acc[n] = MFMA(a, bv, acc[n]);
      }
    }
    if (ph < 15) write_ph(buf ^ 1);        // write-late (after compute)
    __syncthreads();
  }
  size_t prow = (size_t)hc*1024 + mb*64 + wv*16;
  #pragma unroll
  for (int j = 0; j < 4; ++j) {
    int rloc = qq*4 + j;
    #pragma unroll
    for (int n = 0; n < 4; ++n)
      atomicAdd(&pnum[(prow + rloc)*64 + 16*n + lm], acc[n][j]);
    if (lm == 0) atomicAdd(&pden[prow + rloc], acc[4][j]);
  }
}

// ---------------------------------------------------------------------------
// finalize (chunks 1..3): out = (intra_num + pnum) / max(row + pden, eps)
// ---------------------------------------------------------------------------
__global__ __launch_bounds__(256) void finalize_kernel(const float* __restrict__ rowp,
    const float* __restrict__ pnum, const float* __restrict__ pden,
    float* __restrict__ out) {
  int idx = blockIdx.x*256 + threadIdx.x;
  int e4 = idx*4;
  int row = e4 >> 6;                  // hc*1024 + rg
  int col = e4 & 63;
  int hc = row >> 10, rg = row & 1023;
  int slab = hc >> 3, h = hc & 7, c = slab + 1;
  float dinv = 1.f / fmaxf(rowp[(c*NH + h)*CL + rg] + pden[row], KEPS);
  f32x4 pv = *(const f32x4*)&pnum[e4];
  size_t ob = ((size_t)(c*CL + rg)*NH + h)*ND + col;
  f32x4 ov = *(const f32x4*)&out[ob];
  #pragma unroll
  for (int j = 0; j < 4; ++j) ov[j] = (ov[j] + pv[j]) * dinv;
  *(f32x4*)&out[ob] = ov;
}

// ---------------------------------------------------------------------------
extern "C" void kernel_launch(void* const* d_in, const int* in_sizes, int n_in,
                              void* d_out, int out_size, void* d_ws, size_t ws_size,
                              hipStream_t stream) {
  const float* q  = (const float*)d_in[0];
  const float* k  = (const float*)d_in[1];
  const float* v  = (const float*)d_in[2];
  const float* lg = (const float*)d_in[3];
  float* out = (float*)d_out;

  float* wf    = (float*)d_ws;
  float* g_arr = wf;                       // 32768 f32
  float* gend  = g_arr + 32768;            // 32
  float* gtot  = gend + 32;                // 32
  float* rowp  = gtot + 32;                // 32768
  float* pden  = rowp + 32768;             // 24576
  float* pnum  = pden + 24576;             // 1,572,864
  __bf16* qgb  = (__bf16*)(pnum + 1572864);// 2,097,152 bf16 each
  __bf16* kgb  = qgb + 2097152;
  __bf16* kht  = kgb + 2097152;
  __bf16* vt   = kht + 2097152;            // 4*8*80*1024 = 2,621,440
  __bf16* st   = vt + 2621440;             // 3*8*80*4096 = 7,864,320
  // total ~40.2 MB

  hipMemsetAsync(pden, 0, (size_t)(24576 + 1572864)*sizeof(float), stream);
  gate_kernel<<<dim3(NC*NH), dim3(CL), 0, stream>>>(lg, g_arr, gend, gtot);
  convert_kernel<<<dim3(16, NH, NC), dim3(256), 0, stream>>>(q, k, v, g_arr, gend, qgb, kgb, kht, vt);
  intra_kernel<<<dim3(16, NH, NC), dim3(256), 0, stream>>>(qgb, kgb, vt, out, rowp);
  pzscan_kernel<<<dim3(32, NH), dim3(256), 0, stream>>>(kht, vt, gtot, st);
  inter_partial_kernel<<<dim3(16, 4, 24), dim3(256), 0, stream>>>(qgb, st, pnum, pden);
  finalize_kernel<<<dim3(1536), dim3(256), 0, stream>>>(rowp, pnum, pden, out);
}

// Round 9
// 211.953 us; speedup vs baseline: 14.7012x; 1.0171x over previous
//
#include <hip/hip_runtime.h>
#include <math.h>

typedef float f32x4 __attribute__((ext_vector_type(4)));
typedef __bf16 bf16x8 __attribute__((ext_vector_type(8)));
typedef __bf16 bf16x4 __attribute__((ext_vector_type(4)));

namespace {
constexpr int NC = 4, CL = 1024, NH = 8, ND = 64;
constexpr float KSCALE = 0.125f, KEPS = 1e-6f;
constexpr int PQ = 72;   // LDS pitch (bf16) for [*][64] tiles: 144B rows, 16B-aligned
constexpr int PK = 40;   // LDS pitch (bf16) for [*][32] tiles: 80B rows, 16B-aligned
}

#define MFMA(a,b,c) __builtin_amdgcn_mfma_f32_16x16x32_bf16((a),(b),(c),0,0,0)

// ---------------------------------------------------------------------------
// gate: per (c,h) inclusive cumsum of log_g; write g, g_end, exp(g_end)
// ---------------------------------------------------------------------------
__global__ __launch_bounds__(1024) void gate_kernel(const float* __restrict__ lg,
    float* __restrict__ g_arr, float* __restrict__ gend, float* __restrict__ gtot) {
  int c = blockIdx.x >> 3, h = blockIdx.x & 7;
  int l = threadIdx.x;
  __shared__ float sm[CL];
  sm[l] = lg[(c*CL + l)*NH + h];
  __syncthreads();
  for (int off = 1; off < CL; off <<= 1) {
    float t = (l >= off) ? sm[l-off] : 0.f;
    __syncthreads();
    sm[l] += t;
    __syncthreads();
  }
  g_arr[(c*NH + h)*CL + l] = sm[l];
  if (l == 0) { gend[c*NH+h] = sm[CL-1]; gtot[c*NH+h] = expf(sm[CL-1]); }
}

// ---------------------------------------------------------------------------
// convert: bf16 operand arrays.
//   qgb[ch][l][d] = q*SCALE*exp(g/2)        (intra QK B-op, inter A-gen)
//   kgb[ch][l][d] = k*exp(-g/2)             (intra QK A-op)
//   kht[ch][d][l] = k*exp((gend-g)/2)       (pzscan A-gen, transposed)
//   vt [ch][p][l] p<64: v^T; p=64: ones; p=65..79: zeros  (B-op everywhere)
// ---------------------------------------------------------------------------
__global__ __launch_bounds__(256) void convert_kernel(const float* __restrict__ q,
    const float* __restrict__ k, const float* __restrict__ v,
    const float* __restrict__ g_arr, const float* __restrict__ gend,
    __bf16* __restrict__ qgb, __bf16* __restrict__ kgb,
    __bf16* __restrict__ kht, __bf16* __restrict__ vt) {
  int lt = blockIdx.x, h = blockIdx.y, c = blockIdx.z;
  int ch = c*NH + h;
  int t = threadIdx.x;
  __shared__ float ld[64][65];
  int lr = t >> 2, sg = t & 3;
  int l = lt*64 + lr;
  size_t ib = ((size_t)(c*CL + l)*NH + h)*ND + sg*16;
  float ge = gend[ch];
  float gl = g_arr[ch*CL + l];
  float eq = expf(0.5f*gl), ekk = expf(-0.5f*gl), ew = expf(0.5f*(ge-gl));
  float qv[16], kv[16], vv[16];
  #pragma unroll
  for (int i = 0; i < 4; ++i) {
    *(f32x4*)&qv[4*i] = *(const f32x4*)&q[ib+4*i];
    *(f32x4*)&kv[4*i] = *(const f32x4*)&k[ib+4*i];
    *(f32x4*)&vv[4*i] = *(const f32x4*)&v[ib+4*i];
  }
  size_t ob = ((size_t)ch*CL + l)*ND + sg*16;
  {
    bf16x8 a, b;
    #pragma unroll
    for (int i = 0; i < 8; ++i) { a[i]=(__bf16)(qv[i]*KSCALE*eq); b[i]=(__bf16)(qv[8+i]*KSCALE*eq); }
    *(bf16x8*)&qgb[ob] = a; *(bf16x8*)&qgb[ob+8] = b;
    #pragma unroll
    for (int i = 0; i < 8; ++i) { a[i]=(__bf16)(kv[i]*ekk); b[i]=(__bf16)(kv[8+i]*ekk); }
    *(bf16x8*)&kgb[ob] = a; *(bf16x8*)&kgb[ob+8] = b;
  }
  // kht transpose via LDS
  #pragma unroll
  for (int i = 0; i < 16; ++i) ld[lr][sg*16+i] = kv[i]*ew;
  __syncthreads();
  {
    int d = t >> 2, s2 = t & 3;
    bf16x8 a, b;
    #pragma unroll
    for (int i = 0; i < 8; ++i) { a[i]=(__bf16)ld[s2*16+i][d]; b[i]=(__bf16)ld[s2*16+8+i][d]; }
    size_t kb = ((size_t)ch*ND + d)*CL + lt*64 + s2*16;
    *(bf16x8*)&kht[kb] = a; *(bf16x8*)&kht[kb+8] = b;
  }
  __syncthreads();
  // vt transpose via LDS
  #pragma unroll
  for (int i = 0; i < 16; ++i) ld[lr][sg*16+i] = vv[i];
  __syncthreads();
  {
    int p = t >> 2, s2 = t & 3;
    bf16x8 a, b;
    #pragma unroll
    for (int i = 0; i < 8; ++i) { a[i]=(__bf16)ld[s2*16+i][p]; b[i]=(__bf16)ld[s2*16+8+i][p]; }
    size_t vb = ((size_t)ch*80 + p)*CL + lt*64 + s2*16;
    *(bf16x8*)&vt[vb] = a; *(bf16x8*)&vt[vb+8] = b;
  }
  if (t < 64) vt[((size_t)ch*80 + 64)*CL + lt*64 + t] = (__bf16)1.0f;
  for (int idx = t; idx < 15*64; idx += 256)
    vt[((size_t)ch*80 + 65 + idx/64)*CL + lt*64 + (idx & 63)] = (__bf16)0.0f;
}

// ---------------------------------------------------------------------------
// intra v2: causal, single-barrier double-buffered pipeline.
// score=(qg.kg)^2 (gating prefolded). Swapped mfma(kg,qg), square+mask,
// per-wave As bounce (no barrier needed), A@V with vt (col64=rowsum).
// ---------------------------------------------------------------------------
__global__ __launch_bounds__(256) void intra_kernel(const __bf16* __restrict__ qgb,
    const __bf16* __restrict__ kgb, const __bf16* __restrict__ vt,
    float* __restrict__ out, float* __restrict__ rowp) {
  int rt = blockIdx.x, h = blockIdx.y, c = blockIdx.z;
  int ch = c*NH + h;
  int t = threadIdx.x, wv = t >> 6, lane = t & 63, qq = lane >> 4, lm = lane & 15;
  __shared__ __align__(16) __bf16 qt[64*PQ];
  __shared__ __align__(16) __bf16 kgl[2][32*PQ];
  __shared__ __align__(16) __bf16 vtl[2][80*PK];
  __shared__ __align__(16) __bf16 As[64*PK];
  int nst = 2*rt + 2;
  // staging coords
  int r8 = t >> 3, sg8 = t & 7;   // kgl: 32 rows x 64 cols
  int r4 = t >> 2, s4 = t & 3;    // vtl: 80 rows x 32 cols
  bf16x8 rkg, rva, rvb;
  auto load_it = [&](int s3) {
    rkg = *(const bf16x8*)&kgb[((size_t)ch*CL + s3*32 + r8)*ND + sg8*8];
    rva = *(const bf16x8*)&vt[((size_t)ch*80 + r4)*CL + s3*32 + s4*8];
    if (t < 64) rvb = *(const bf16x8*)&vt[((size_t)ch*80 + 64 + r4)*CL + s3*32 + s4*8];
  };
  auto write_it = [&](int buf) {
    *(bf16x8*)&kgl[buf][r8*PQ + sg8*8] = rkg;
    *(bf16x8*)&vtl[buf][r4*PK + s4*8] = rva;
    if (t < 64) *(bf16x8*)&vtl[buf][(64+r4)*PK + s4*8] = rvb;
  };
  {
    int r = t >> 2, sg = t & 3;
    size_t gb = ((size_t)ch*CL + rt*64 + r)*ND + sg*16;
    *(bf16x8*)&qt[r*PQ + sg*16]     = *(const bf16x8*)&qgb[gb];
    *(bf16x8*)&qt[r*PQ + sg*16 + 8] = *(const bf16x8*)&qgb[gb+8];
  }
  load_it(0);
  write_it(0);
  __syncthreads();
  bf16x8 bq0 = *(bf16x8*)&qt[(wv*16+lm)*PQ + qq*8];
  bf16x8 bq1 = *(bf16x8*)&qt[(wv*16+lm)*PQ + 32 + qq*8];
  f32x4 acc[5];
  #pragma unroll
  for (int n = 0; n < 5; ++n) acc[n] = (f32x4){0.f,0.f,0.f,0.f};
  int r_gc = rt*64 + wv*16 + lm;
  int buf = 0;
  for (int s3 = 0; s3 < nst; ++s3) {
    if (s3 + 1 < nst) load_it(s3 + 1);          // issue next-tile loads early
    #pragma unroll
    for (int ss = 0; ss < 2; ++ss) {
      f32x4 dr = (f32x4){0.f,0.f,0.f,0.f};
      bf16x8 a0 = *(bf16x8*)&kgl[buf][(ss*16+lm)*PQ + qq*8];
      bf16x8 a1 = *(bf16x8*)&kgl[buf][(ss*16+lm)*PQ + 32 + qq*8];
      dr = MFMA(a0, bq0, dr);
      dr = MFMA(a1, bq1, dr);
      bf16x4 pk;
      #pragma unroll
      for (int j = 0; j < 4; ++j) {
        int s_g = s3*32 + ss*16 + qq*4 + j;
        float dv = dr[j];
        pk[j] = (__bf16)((s_g <= r_gc) ? dv*dv : 0.f);
      }
      *(bf16x4*)&As[(wv*16+lm)*PK + ss*16 + qq*4] = pk;
    }
    bf16x8 aav = *(bf16x8*)&As[(wv*16+lm)*PK + qq*8];
    #pragma unroll
    for (int n = 0; n < 5; ++n) {
      bf16x8 bv = *(bf16x8*)&vtl[buf][(n*16+lm)*PK + qq*8];
      acc[n] = MFMA(aav, bv, acc[n]);
    }
    if (s3 + 1 < nst) write_it(buf ^ 1);        // write-late
    __syncthreads();
    buf ^= 1;
  }
  if (c == 0) {
    #pragma unroll
    for (int j = 0; j < 4; ++j) {
      float rs = __shfl(acc[4][j], lane & 48, 64);
      float dinv = 1.f / fmaxf(rs, KEPS);
      int rg = rt*64 + wv*16 + qq*4 + j;
      size_t ob = ((size_t)(c*CL + rg)*NH + h)*ND + lm;
      #pragma unroll
      for (int n = 0; n < 4; ++n) out[ob + 16*n] = acc[n][j]*dinv;
    }
  } else {
    #pragma unroll
    for (int j = 0; j < 4; ++j) {
      int rg = rt*64 + wv*16 + qq*4 + j;
      size_t ob = ((size_t)(c*CL + rg)*NH + h)*ND + lm;
      #pragma unroll
      for (int n = 0; n < 4; ++n) out[ob + 16*n] = acc[n][j];
      if (lm == 0) rowp[ch*CL + rg] = acc[4][j];
    }
  }
}

// ---------------------------------------------------------------------------
// pzscan v3: v-split 2-way for occupancy (512 blocks = 2/CU; round-8 was
// 256 = 1/CU, fully latency-exposed). Scan S[d,e,v] is element-independent
// in v, so vs=0 owns v-tiles {0,1} (st rows 0-31), vs=1 owns {2,3,4}
// (st rows 32-63 + sk row 64). Same 96-iter single-barrier pipeline.
// ---------------------------------------------------------------------------
template<int NT, int VBASE>
__device__ __forceinline__ void pzscan_body(
    const __bf16* __restrict__ kht, const __bf16* __restrict__ vt,
    const float* __restrict__ gtot, __bf16* __restrict__ st,
    int mblk, int h,
    __bf16 (*ke)[64*PK], __bf16 (*kd)[2*PK], __bf16 (*vtl)[48*PK],
    float (*tb)[40]) {
  constexpr int NROW = NT*16;
  int t = threadIdx.x, wv = t >> 6, lane = t & 63, qq = lane >> 4, lm = lane & 15;
  int dl = wv >> 1, e0w = (wv & 1)*32;
  int r = t >> 2, cg = t & 3;
  bf16x8 rke, rva, rkd;
  auto load_it = [&](int it) {
    int cc = it >> 5, kk = it & 31;
    int ch = cc*NH + h;
    int l0 = kk*32;
    rke = *(const bf16x8*)&kht[((size_t)ch*ND + r)*CL + l0 + cg*8];
    if (r < NROW) rva = *(const bf16x8*)&vt[((size_t)ch*80 + VBASE + r)*CL + l0 + cg*8];
    if (t < 8)  rkd = *(const bf16x8*)&kht[((size_t)ch*ND + mblk*2 + (t>>2))*CL + l0 + (t&3)*8];
  };
  auto write_it = [&](int buf) {
    *(bf16x8*)&ke[buf][r*PK + cg*8] = rke;
    if (r < NROW) *(bf16x8*)&vtl[buf][r*PK + cg*8] = rva;
    if (t < 8)  *(bf16x8*)&kd[buf][(t>>2)*PK + (t&3)*8] = rkd;
  };
  f32x4 S_reg[2][NT], acc[2][NT];
  #pragma unroll
  for (int m = 0; m < 2; ++m)
    #pragma unroll
    for (int n = 0; n < NT; ++n) {
      S_reg[m][n] = (f32x4){0.f,0.f,0.f,0.f};
      acc[m][n] = (f32x4){0.f,0.f,0.f,0.f};
    }
  load_it(0);
  write_it(0);
  __syncthreads();
  int buf = 0;
  for (int it = 0; it < 96; ++it) {
    if (it < 95) load_it(it + 1);          // issue next-tile loads early
    bf16x8 kd8 = *(bf16x8*)&kd[buf][dl*PK + qq*8];
    bf16x8 am[2];
    #pragma unroll
    for (int m = 0; m < 2; ++m) {
      bf16x8 ke8 = *(bf16x8*)&ke[buf][(e0w + 16*m + lm)*PK + qq*8];
      bf16x8 a;
      #pragma unroll
      for (int i = 0; i < 8; ++i) a[i] = (__bf16)((float)kd8[i] * (float)ke8[i]);
      am[m] = a;
    }
    #pragma unroll
    for (int n = 0; n < NT; ++n) {
      bf16x8 bv = *(bf16x8*)&vtl[buf][(16*n+lm)*PK + qq*8];
      acc[0][n] = MFMA(am[0], bv, acc[0][n]);
      acc[1][n] = MFMA(am[1], bv, acc[1][n]);
    }
    if (it < 95) write_it(buf ^ 1);        // write-late
    __syncthreads();
    buf ^= 1;
    if ((it & 31) == 31) {
      int cc = it >> 5;
      float gt = gtot[cc*NH + h];
      #pragma unroll
      for (int m = 0; m < 2; ++m)
        #pragma unroll
        for (int n = 0; n < NT; ++n)
          #pragma unroll
          for (int j = 0; j < 4; ++j) {
            S_reg[m][n][j] = gt*S_reg[m][n][j] + acc[m][n][j];
            acc[m][n][j] = 0.f;
          }
      // write st slab cc: rows v = VBASE..VBASE+31 via tb transpose, 2 d-halves
      size_t slab = (size_t)(cc*NH + h)*80;
      for (int h2 = 0; h2 < 2; ++h2) {
        __syncthreads();
        if (dl == h2) {
          #pragma unroll
          for (int m = 0; m < 2; ++m)
            #pragma unroll
            for (int n = 0; n < 2; ++n)
              #pragma unroll
              for (int j = 0; j < 4; ++j)
                tb[e0w + 16*m + qq*4 + j][16*n + lm] = S_reg[m][n][j];
        }
        __syncthreads();
        {
          int vr = t >> 3, eg = t & 7;
          bf16x8 a;
          #pragma unroll
          for (int i = 0; i < 8; ++i) a[i] = (__bf16)tb[eg*8+i][vr];
          *(bf16x8*)&st[(slab + VBASE + vr)*4096 + (size_t)(mblk*2 + h2)*64 + eg*8] = a;
        }
      }
      if (NT == 3 && lm == 0) {
        #pragma unroll
        for (int m = 0; m < 2; ++m)
          #pragma unroll
          for (int j = 0; j < 4; ++j)
            st[(slab + 64)*4096 + (size_t)(mblk*2 + dl)*64 + e0w + 16*m + qq*4 + j] =
              (__bf16)S_reg[m][2][j];
      }
    }
  }
}

__global__ __launch_bounds__(256) void pzscan_kernel(const __bf16* __restrict__ kht,
    const __bf16* __restrict__ vt, const float* __restrict__ gtot,
    __bf16* __restrict__ st) {
  __shared__ __align__(16) __bf16 ke[2][64*PK];
  __shared__ __align__(16) __bf16 kd[2][2*PK];
  __shared__ __align__(16) __bf16 vtl[2][48*PK];
  __shared__ float tb[64][40];
  if (blockIdx.y == 0)
    pzscan_body<2, 0>(kht, vt, gtot, st, blockIdx.x, blockIdx.z, ke, kd, vtl, tb);
  else
    pzscan_body<3, 32>(kht, vt, gtot, st, blockIdx.x, blockIdx.z, ke, kd, vtl, tb);
}

// ---------------------------------------------------------------------------
// inter_partial (chunks 1..3, K split 4-way): partial phi(qg)@S into pnum/pden
// via f32 atomics. Per block: 64 q-rows x 65 cols x 16 d-phases (K=1024).
// Single-barrier double-buffered LDS pipeline; A-gen inputs all in registers.
// ---------------------------------------------------------------------------
__global__ __launch_bounds__(256) void inter_partial_kernel(
    const __bf16* __restrict__ qgb, const __bf16* __restrict__ st,
    float* __restrict__ pnum, float* __restrict__ pden) {
  int mb = blockIdx.x;          // 0..15 : 64-row tile
  int ks = blockIdx.y;          // 0..3  : K quarter (16 d values)
  int hc = blockIdx.z;          // 0..23 : slab*8 + h
  int slab = hc >> 3, h = hc & 7;
  int c = slab + 1, ch = c*NH + h;
  int t = threadIdx.x, wv = t >> 6, lane = t & 63, qq = lane >> 4, lm = lane & 15;
  __shared__ __align__(16) __bf16 stl[2][65*PQ];
  size_t slabbase = (size_t)(slab*NH + h)*80;
  // per-lane q-row operands, hoisted once (e-range identical every phase)
  int rrow = mb*64 + wv*16 + lm;
  size_t qb = ((size_t)ch*CL + rrow)*ND;
  bf16x8 qe0 = *(const bf16x8*)&qgb[qb + qq*8];
  bf16x8 qe1 = *(const bf16x8*)&qgb[qb + 32 + qq*8];
  float qd[16];
  {
    bf16x8 qa = *(const bf16x8*)&qgb[qb + ks*16];
    bf16x8 qbv = *(const bf16x8*)&qgb[qb + ks*16 + 8];
    #pragma unroll
    for (int i = 0; i < 8; ++i) { qd[i] = (float)qa[i]; qd[8+i] = (float)qbv[i]; }
  }
  int r = t >> 2, cg = t & 3;
  bf16x8 sa, sb, sc;
  auto load_ph = [&](int ph) {
    size_t base = (slabbase + r)*4096 + (size_t)(ks*16 + ph)*64 + cg*16;
    sa = *(const bf16x8*)&st[base];
    sb = *(const bf16x8*)&st[base + 8];
    if (t < 8) sc = *(const bf16x8*)&st[(slabbase + 64)*4096 + (size_t)(ks*16 + ph)*64 + t*8];
  };
  auto write_ph = [&](int buf) {
    *(bf16x8*)&stl[buf][r*PQ + cg*16]     = sa;
    *(bf16x8*)&stl[buf][r*PQ + cg*16 + 8] = sb;
    if (t < 8) *(bf16x8*)&stl[buf][64*PQ + t*8] = sc;
  };
  f32x4 acc[5];
  #pragma unroll
  for (int n = 0; n < 5; ++n) acc[n] = (f32x4){0.f,0.f,0.f,0.f};
  load_ph(0);
  write_ph(0);
  __syncthreads();
  #pragma unroll
  for (int ph = 0; ph < 16; ++ph) {
    int buf = ph & 1;
    if (ph < 15) load_ph(ph + 1);          // issue next-phase loads early
    float qdv = qd[ph];
    #pragma unroll
    for (int s = 0; s < 2; ++s) {
      bf16x8 qe = s ? qe1 : qe0;
      bf16x8 a;
      #pragma unroll
      for (int i = 0; i < 8; ++i) a[i] = (__bf16)(qdv * (float)qe[i]);
      #pragma unroll
      for (int n = 0; n < 5; ++n) {
        bf16x8 bv = *(bf16x8*)&stl[buf][(16*n + lm)*PQ + s*32 + qq*8];
        acc[n] = MFMA(a, bv, acc[n]);
      }
    }
    if (ph < 15) write_ph(buf ^ 1);        // write-late (after compute)
    __syncthreads();
  }
  size_t prow = (size_t)hc*1024 + mb*64 + wv*16;
  #pragma unroll
  for (int j = 0; j < 4; ++j) {
    int rloc = qq*4 + j;
    #pragma unroll
    for (int n = 0; n < 4; ++n)
      atomicAdd(&pnum[(prow + rloc)*64 + 16*n + lm], acc[n][j]);
    if (lm == 0) atomicAdd(&pden[prow + rloc], acc[4][j]);
  }
}

// ---------------------------------------------------------------------------
// finalize (chunks 1..3): out = (intra_num + pnum) / max(row + pden, eps)
// ---------------------------------------------------------------------------
__global__ __launch_bounds__(256) void finalize_kernel(const float* __restrict__ rowp,
    const float* __restrict__ pnum, const float* __restrict__ pden,
    float* __restrict__ out) {
  int idx = blockIdx.x*256 + threadIdx.x;
  int e4 = idx*4;
  int row = e4 >> 6;                  // hc*1024 + rg
  int col = e4 & 63;
  int hc = row >> 10, rg = row & 1023;
  int slab = hc >> 3, h = hc & 7, c = slab + 1;
  float dinv = 1.f / fmaxf(rowp[(c*NH + h)*CL + rg] + pden[row], KEPS);
  f32x4 pv = *(const f32x4*)&pnum[e4];
  size_t ob = ((size_t)(c*CL + rg)*NH + h)*ND + col;
  f32x4 ov = *(const f32x4*)&out[ob];
  #pragma unroll
  for (int j = 0; j < 4; ++j) ov[j] = (ov[j] + pv[j]) * dinv;
  *(f32x4*)&out[ob] = ov;
}

// ---------------------------------------------------------------------------
extern "C" void kernel_launch(void* const* d_in, const int* in_sizes, int n_in,
                              void* d_out, int out_size, void* d_ws, size_t ws_size,
                              hipStream_t stream) {
  const float* q  = (const float*)d_in[0];
  const float* k  = (const float*)d_in[1];
  const float* v  = (const float*)d_in[2];
  const float* lg = (const float*)d_in[3];
  float* out = (float*)d_out;

  float* wf    = (float*)d_ws;
  float* g_arr = wf;                       // 32768 f32
  float* gend  = g_arr + 32768;            // 32
  float* gtot  = gend + 32;                // 32
  float* rowp  = gtot + 32;                // 32768
  float* pden  = rowp + 32768;             // 24576
  float* pnum  = pden + 24576;             // 1,572,864
  __bf16* qgb  = (__bf16*)(pnum + 1572864);// 2,097,152 bf16 each
  __bf16* kgb  = qgb + 2097152;
  __bf16* kht  = kgb + 2097152;
  __bf16* vt   = kht + 2097152;            // 4*8*80*1024 = 2,621,440
  __bf16* st   = vt + 2621440;             // 3*8*80*4096 = 7,864,320
  // total ~40.2 MB

  hipMemsetAsync(pden, 0, (size_t)(24576 + 1572864)*sizeof(float), stream);
  gate_kernel<<<dim3(NC*NH), dim3(CL), 0, stream>>>(lg, g_arr, gend, gtot);
  convert_kernel<<<dim3(16, NH, NC), dim3(256), 0, stream>>>(q, k, v, g_arr, gend, qgb, kgb, kht, vt);
  intra_kernel<<<dim3(16, NH, NC), dim3(256), 0, stream>>>(qgb, kgb, vt, out, rowp);
  pzscan_kernel<<<dim3(32, 2, NH), dim3(256), 0, stream>>>(kht, vt, gtot, st);
  inter_partial_kernel<<<dim3(16, 4, 24), dim3(256), 0, stream>>>(qgb, st, pnum, pden);
  finalize_kernel<<<dim3(1536), dim3(256), 0, stream>>>(rowp, pnum, pden, out);
}

// Round 10
// 196.094 us; speedup vs baseline: 15.8902x; 1.0809x over previous
//
#include <hip/hip_runtime.h>
#include <math.h>

typedef float f32x4 __attribute__((ext_vector_type(4)));
typedef __bf16 bf16x8 __attribute__((ext_vector_type(8)));
typedef __bf16 bf16x4 __attribute__((ext_vector_type(4)));

namespace {
constexpr int NC = 4, CL = 1024, NH = 8, ND = 64;
constexpr float KSCALE = 0.125f, KEPS = 1e-6f;
constexpr int PQ = 72;   // LDS pitch (bf16) for [*][64] tiles
constexpr int PK = 40;   // LDS pitch (bf16) for [*][32] tiles
}

#define MFMA(a,b,c) __builtin_amdgcn_mfma_f32_16x16x32_bf16((a),(b),(c),0,0,0)

// ---------------------------------------------------------------------------
// gate: per (c,h) inclusive cumsum of log_g; write g, g_end, exp(g_end)
// ---------------------------------------------------------------------------
__global__ __launch_bounds__(1024) void gate_kernel(const float* __restrict__ lg,
    float* __restrict__ g_arr, float* __restrict__ gend, float* __restrict__ gtot) {
  int c = blockIdx.x >> 3, h = blockIdx.x & 7;
  int l = threadIdx.x;
  __shared__ float sm[CL];
  sm[l] = lg[(c*CL + l)*NH + h];
  __syncthreads();
  for (int off = 1; off < CL; off <<= 1) {
    float t = (l >= off) ? sm[l-off] : 0.f;
    __syncthreads();
    sm[l] += t;
    __syncthreads();
  }
  g_arr[(c*NH + h)*CL + l] = sm[l];
  if (l == 0) { gend[c*NH+h] = sm[CL-1]; gtot[c*NH+h] = expf(sm[CL-1]); }
}

// ---------------------------------------------------------------------------
// convert: bf16 operand arrays.
//   qgb[ch][l][d] = q*SCALE*exp(g/2)        (intra QK B-op, inter A-gen)
//   kgb[ch][l][d] = k*exp(-g/2)             (intra QK A-op)
//   kht[ch][d][l] = k*exp((gend-g)/2)       (pz A-gen, transposed)
//   vt [ch][p][l] p<64: v^T; p=64: ones; p=65..79: zeros  (B-op everywhere)
// ---------------------------------------------------------------------------
__global__ __launch_bounds__(256) void convert_kernel(const float* __restrict__ q,
    const float* __restrict__ k, const float* __restrict__ v,
    const float* __restrict__ g_arr, const float* __restrict__ gend,
    __bf16* __restrict__ qgb, __bf16* __restrict__ kgb,
    __bf16* __restrict__ kht, __bf16* __restrict__ vt) {
  int lt = blockIdx.x, h = blockIdx.y, c = blockIdx.z;
  int ch = c*NH + h;
  int t = threadIdx.x;
  __shared__ float ld[64][65];
  int lr = t >> 2, sg = t & 3;
  int l = lt*64 + lr;
  size_t ib = ((size_t)(c*CL + l)*NH + h)*ND + sg*16;
  float ge = gend[ch];
  float gl = g_arr[ch*CL + l];
  float eq = expf(0.5f*gl), ekk = expf(-0.5f*gl), ew = expf(0.5f*(ge-gl));
  float qv[16], kv[16], vv[16];
  #pragma unroll
  for (int i = 0; i < 4; ++i) {
    *(f32x4*)&qv[4*i] = *(const f32x4*)&q[ib+4*i];
    *(f32x4*)&kv[4*i] = *(const f32x4*)&k[ib+4*i];
    *(f32x4*)&vv[4*i] = *(const f32x4*)&v[ib+4*i];
  }
  size_t ob = ((size_t)ch*CL + l)*ND + sg*16;
  {
    bf16x8 a, b;
    #pragma unroll
    for (int i = 0; i < 8; ++i) { a[i]=(__bf16)(qv[i]*KSCALE*eq); b[i]=(__bf16)(qv[8+i]*KSCALE*eq); }
    *(bf16x8*)&qgb[ob] = a; *(bf16x8*)&qgb[ob+8] = b;
    #pragma unroll
    for (int i = 0; i < 8; ++i) { a[i]=(__bf16)(kv[i]*ekk); b[i]=(__bf16)(kv[8+i]*ekk); }
    *(bf16x8*)&kgb[ob] = a; *(bf16x8*)&kgb[ob+8] = b;
  }
  // kht transpose via LDS
  #pragma unroll
  for (int i = 0; i < 16; ++i) ld[lr][sg*16+i] = kv[i]*ew;
  __syncthreads();
  {
    int d = t >> 2, s2 = t & 3;
    bf16x8 a, b;
    #pragma unroll
    for (int i = 0; i < 8; ++i) { a[i]=(__bf16)ld[s2*16+i][d]; b[i]=(__bf16)ld[s2*16+8+i][d]; }
    size_t kb = ((size_t)ch*ND + d)*CL + lt*64 + s2*16;
    *(bf16x8*)&kht[kb] = a; *(bf16x8*)&kht[kb+8] = b;
  }
  __syncthreads();
  // vt transpose via LDS
  #pragma unroll
  for (int i = 0; i < 16; ++i) ld[lr][sg*16+i] = vv[i];
  __syncthreads();
  {
    int p = t >> 2, s2 = t & 3;
    bf16x8 a, b;
    #pragma unroll
    for (int i = 0; i < 8; ++i) { a[i]=(__bf16)ld[s2*16+i][p]; b[i]=(__bf16)ld[s2*16+8+i][p]; }
    size_t vb = ((size_t)ch*80 + p)*CL + lt*64 + s2*16;
    *(bf16x8*)&vt[vb] = a; *(bf16x8*)&vt[vb+8] = b;
  }
  if (t < 64) vt[((size_t)ch*80 + 64)*CL + lt*64 + t] = (__bf16)1.0f;
  for (int idx = t; idx < 15*64; idx += 256)
    vt[((size_t)ch*80 + 65 + idx/64)*CL + lt*64 + (idx & 63)] = (__bf16)0.0f;
}

// ---------------------------------------------------------------------------
// intra v3: balanced. Block (p, hf, c*8+h) processes row-tiles p and 15-p
// sequentially, each with its s-range split in half (hf) -> exactly 17
// s-tile units per block (uniform; XCD = p gets identical totals).
// Partial num/rowsum accumulated via f32 atomics into pnum/pden.
// ---------------------------------------------------------------------------
__global__ __launch_bounds__(256) void intra_kernel(const __bf16* __restrict__ qgb,
    const __bf16* __restrict__ kgb, const __bf16* __restrict__ vt,
    float* __restrict__ pnum, float* __restrict__ pden) {
  int p = blockIdx.x, hf = blockIdx.y;
  int h = blockIdx.z & 7, c = blockIdx.z >> 3;
  int ch = c*NH + h;
  int t = threadIdx.x, wv = t >> 6, lane = t & 63, qq = lane >> 4, lm = lane & 15;
  __shared__ __align__(16) __bf16 qt[64*PQ];
  __shared__ __align__(16) __bf16 kgl[2][32*PQ];
  __shared__ __align__(16) __bf16 vtl[2][80*PK];
  __shared__ __align__(16) __bf16 As[64*PK];
  int r8 = t >> 3, sg8 = t & 7;   // kgl: 32 rows x 64 cols
  int r4 = t >> 2, s4 = t & 3;    // vtl: 80 rows x 32 cols
  bf16x8 rkg, rva, rvb;
  auto load_it = [&](int s3) {
    rkg = *(const bf16x8*)&kgb[((size_t)ch*CL + s3*32 + r8)*ND + sg8*8];
    rva = *(const bf16x8*)&vt[((size_t)ch*80 + r4)*CL + s3*32 + s4*8];
    if (t < 64) rvb = *(const bf16x8*)&vt[((size_t)ch*80 + 64 + r4)*CL + s3*32 + s4*8];
  };
  auto write_it = [&](int buf) {
    *(bf16x8*)&kgl[buf][r8*PQ + sg8*8] = rkg;
    *(bf16x8*)&vtl[buf][r4*PK + s4*8] = rva;
    if (t < 64) *(bf16x8*)&vtl[buf][(64+r4)*PK + s4*8] = rvb;
  };
  for (int ph = 0; ph < 2; ++ph) {
    int rt = ph ? (15 - p) : p;
    int ntile = rt + 1;            // half of this row-tile's 2rt+2 s-tiles
    int s_beg = hf * ntile;
    {
      int r = t >> 2, sg = t & 3;
      size_t gb = ((size_t)ch*CL + rt*64 + r)*ND + sg*16;
      *(bf16x8*)&qt[r*PQ + sg*16]     = *(const bf16x8*)&qgb[gb];
      *(bf16x8*)&qt[r*PQ + sg*16 + 8] = *(const bf16x8*)&qgb[gb+8];
    }
    load_it(s_beg);
    write_it(0);
    __syncthreads();
    bf16x8 bq0 = *(bf16x8*)&qt[(wv*16+lm)*PQ + qq*8];
    bf16x8 bq1 = *(bf16x8*)&qt[(wv*16+lm)*PQ + 32 + qq*8];
    f32x4 acc[5];
    #pragma unroll
    for (int n = 0; n < 5; ++n) acc[n] = (f32x4){0.f,0.f,0.f,0.f};
    int r_gc = rt*64 + wv*16 + lm;
    int buf = 0;
    for (int ii = 0; ii < ntile; ++ii) {
      int s3 = s_beg + ii;
      if (ii + 1 < ntile) load_it(s3 + 1);
      #pragma unroll
      for (int ss = 0; ss < 2; ++ss) {
        f32x4 dr = (f32x4){0.f,0.f,0.f,0.f};
        bf16x8 a0 = *(bf16x8*)&kgl[buf][(ss*16+lm)*PQ + qq*8];
        bf16x8 a1 = *(bf16x8*)&kgl[buf][(ss*16+lm)*PQ + 32 + qq*8];
        dr = MFMA(a0, bq0, dr);
        dr = MFMA(a1, bq1, dr);
        bf16x4 pk;
        #pragma unroll
        for (int j = 0; j < 4; ++j) {
          int s_g = s3*32 + ss*16 + qq*4 + j;
          float dv = dr[j];
          pk[j] = (__bf16)((s_g <= r_gc) ? dv*dv : 0.f);
        }
        *(bf16x4*)&As[(wv*16+lm)*PK + ss*16 + qq*4] = pk;
      }
      bf16x8 aav = *(bf16x8*)&As[(wv*16+lm)*PK + qq*8];
      #pragma unroll
      for (int n = 0; n < 5; ++n) {
        bf16x8 bv = *(bf16x8*)&vtl[buf][(n*16+lm)*PK + qq*8];
        acc[n] = MFMA(aav, bv, acc[n]);
      }
      if (ii + 1 < ntile) write_it(buf ^ 1);
      __syncthreads();
      buf ^= 1;
    }
    #pragma unroll
    for (int j = 0; j < 4; ++j) {
      int rg = rt*64 + wv*16 + qq*4 + j;
      size_t base = ((size_t)ch*CL + rg)*64 + lm;
      #pragma unroll
      for (int n = 0; n < 4; ++n) atomicAdd(&pnum[base + 16*n], acc[n][j]);
      if (lm == 0) atomicAdd(&pden[ch*CL + rg], acc[4][j]);
    }
    __syncthreads();   // protect qt/LDS before next phase overwrites
  }
}

// ---------------------------------------------------------------------------
// pz: P for one (d, h, chunk) -> bf16 st slab (v-major rows, row64 = Z).
// Grid (64,8,3) = 1536 blocks = 6/CU. No phi-gen duplication (d partitioned).
// Single-barrier double-buffered pipeline; tb transpose aliased onto dead
// pipeline LDS after the loop.
// ---------------------------------------------------------------------------
__global__ __launch_bounds__(256) void pz_kernel(const __bf16* __restrict__ kht,
    const __bf16* __restrict__ vt, __bf16* __restrict__ st) {
  int dd = blockIdx.x, h = blockIdx.y, cc = blockIdx.z;
  int ch = cc*NH + h;
  int t = threadIdx.x, wv = t >> 6, lane = t & 63, qq = lane >> 4, lm = lane & 15;
  constexpr int KE_SZ = 2*64*PK;   // bf16 elems
  constexpr int KD_SZ = 2*PK;
  constexpr int VT_SZ = 2*80*PK;
  __shared__ __align__(16) __bf16 smem[KE_SZ + KD_SZ + VT_SZ];  // 23200 B
  __bf16 (*ke)[64*PK]  = reinterpret_cast<__bf16(*)[64*PK]>(&smem[0]);
  __bf16 (*kd)[PK]     = reinterpret_cast<__bf16(*)[PK]>(&smem[KE_SZ]);
  __bf16 (*vtl)[80*PK] = reinterpret_cast<__bf16(*)[80*PK]>(&smem[KE_SZ + KD_SZ]);
  float  (*tb)[65]     = reinterpret_cast<float(*)[65]>(&smem[0]); // post-loop alias (16640B <= 23200B)
  int r = t >> 2, cg = t & 3;
  bf16x8 rke, rva, rvb, rkd;
  auto load_it = [&](int kk) {
    int l0 = kk*32;
    rke = *(const bf16x8*)&kht[((size_t)ch*ND + r)*CL + l0 + cg*8];
    rva = *(const bf16x8*)&vt[((size_t)ch*80 + r)*CL + l0 + cg*8];
    if (t < 64) rvb = *(const bf16x8*)&vt[((size_t)ch*80 + 64 + r)*CL + l0 + cg*8];
    if (t < 4)  rkd = *(const bf16x8*)&kht[((size_t)ch*ND + dd)*CL + l0 + t*8];
  };
  auto write_it = [&](int buf) {
    *(bf16x8*)&ke[buf][r*PK + cg*8] = rke;
    *(bf16x8*)&vtl[buf][r*PK + cg*8] = rva;
    if (t < 64) *(bf16x8*)&vtl[buf][(64+r)*PK + cg*8] = rvb;
    if (t < 4)  *(bf16x8*)&kd[buf][t*8] = rkd;
  };
  f32x4 acc[5];
  #pragma unroll
  for (int n = 0; n < 5; ++n) acc[n] = (f32x4){0.f,0.f,0.f,0.f};
  load_it(0);
  write_it(0);
  __syncthreads();
  int buf = 0;
  for (int kk = 0; kk < 32; ++kk) {
    if (kk < 31) load_it(kk + 1);
    bf16x8 kd8 = *(bf16x8*)&kd[buf][qq*8];
    bf16x8 ke8 = *(bf16x8*)&ke[buf][(wv*16+lm)*PK + qq*8];
    bf16x8 a;
    #pragma unroll
    for (int i = 0; i < 8; ++i) a[i] = (__bf16)((float)kd8[i] * (float)ke8[i]);
    #pragma unroll
    for (int n = 0; n < 5; ++n) {
      bf16x8 bv = *(bf16x8*)&vtl[buf][(16*n+lm)*PK + qq*8];
      acc[n] = MFMA(a, bv, acc[n]);
    }
    if (kk < 31) write_it(buf ^ 1);
    __syncthreads();
    buf ^= 1;
  }
  // transpose (d,e)-major -> v-major via aliased tb
  #pragma unroll
  for (int n = 0; n < 4; ++n)
    #pragma unroll
    for (int j = 0; j < 4; ++j)
      tb[wv*16 + qq*4 + j][16*n + lm] = acc[n][j];
  __syncthreads();
  {
    int vr = t >> 2, es = t & 3;
    bf16x8 a, b;
    #pragma unroll
    for (int i = 0; i < 8; ++i) { a[i] = (__bf16)tb[es*16+i][vr]; b[i] = (__bf16)tb[es*16+8+i][vr]; }
    size_t sb = ((size_t)ch*80 + vr)*4096 + (size_t)dd*64 + es*16;
    *(bf16x8*)&st[sb] = a; *(bf16x8*)&st[sb+8] = b;
  }
  if (lm == 0) {
    #pragma unroll
    for (int j = 0; j < 4; ++j)
      st[((size_t)ch*80 + 64)*4096 + (size_t)dd*64 + wv*16 + qq*4 + j] = (__bf16)acc[4][j];
  }
}

// ---------------------------------------------------------------------------
// scan: in-place decayed prefix over chunk slabs: st[c] = gt_c*st[c-1] + st[c]
// (elementwise, f32 math on bf16 storage; covers sk row 64 identically).
// ---------------------------------------------------------------------------
__global__ __launch_bounds__(256) void scan_kernel(const float* __restrict__ gtot,
    __bf16* __restrict__ st) {
  int h = blockIdx.y;
  size_t off = ((size_t)blockIdx.x*256 + threadIdx.x)*8;
  float g1 = gtot[NH + h], g2 = gtot[2*NH + h];
  size_t b0 = ((size_t)(0*NH + h)*80)*4096 + off;
  size_t b1 = ((size_t)(1*NH + h)*80)*4096 + off;
  size_t b2 = ((size_t)(2*NH + h)*80)*4096 + off;
  bf16x8 p0 = *(bf16x8*)&st[b0];
  bf16x8 p1 = *(bf16x8*)&st[b1];
  bf16x8 p2 = *(bf16x8*)&st[b2];
  bf16x8 o1, o2;
  #pragma unroll
  for (int i = 0; i < 8; ++i) {
    float v1 = g1*(float)p0[i] + (float)p1[i];
    o1[i] = (__bf16)v1;
    o2[i] = (__bf16)(g2*v1 + (float)p2[i]);
  }
  *(bf16x8*)&st[b1] = o1;
  *(bf16x8*)&st[b2] = o2;
}

// ---------------------------------------------------------------------------
// inter_partial (chunks 1..3, K split 4-way): partial phi(qg)@S into pnum/pden
// via f32 atomics. Single-barrier double-buffered LDS pipeline.
// ---------------------------------------------------------------------------
__global__ __launch_bounds__(256) void inter_partial_kernel(
    const __bf16* __restrict__ qgb, const __bf16* __restrict__ st,
    float* __restrict__ pnum, float* __restrict__ pden) {
  int mb = blockIdx.x;          // 0..15 : 64-row tile
  int ks = blockIdx.y;          // 0..3  : K quarter (16 d values)
  int hc = blockIdx.z;          // 0..23 : slab*8 + h
  int slab = hc >> 3, h = hc & 7;
  int c = slab + 1, ch = c*NH + h;
  int t = threadIdx.x, wv = t >> 6, lane = t & 63, qq = lane >> 4, lm = lane & 15;
  __shared__ __align__(16) __bf16 stl[2][65*PQ];
  size_t slabbase = (size_t)(slab*NH + h)*80;
  int rrow = mb*64 + wv*16 + lm;
  size_t qb = ((size_t)ch*CL + rrow)*ND;
  bf16x8 qe0 = *(const bf16x8*)&qgb[qb + qq*8];
  bf16x8 qe1 = *(const bf16x8*)&qgb[qb + 32 + qq*8];
  float qd[16];
  {
    bf16x8 qa = *(const bf16x8*)&qgb[qb + ks*16];
    bf16x8 qbv = *(const bf16x8*)&qgb[qb + ks*16 + 8];
    #pragma unroll
    for (int i = 0; i < 8; ++i) { qd[i] = (float)qa[i]; qd[8+i] = (float)qbv[i]; }
  }
  int r = t >> 2, cg = t & 3;
  bf16x8 sa, sb, sc;
  auto load_ph = [&](int ph) {
    size_t base = (slabbase + r)*4096 + (size_t)(ks*16 + ph)*64 + cg*16;
    sa = *(const bf16x8*)&st[base];
    sb = *(const bf16x8*)&st[base + 8];
    if (t < 8) sc = *(const bf16x8*)&st[(slabbase + 64)*4096 + (size_t)(ks*16 + ph)*64 + t*8];
  };
  auto write_ph = [&](int buf) {
    *(bf16x8*)&stl[buf][r*PQ + cg*16]     = sa;
    *(bf16x8*)&stl[buf][r*PQ + cg*16 + 8] = sb;
    if (t < 8) *(bf16x8*)&stl[buf][64*PQ + t*8] = sc;
  };
  f32x4 acc[5];
  #pragma unroll
  for (int n = 0; n < 5; ++n) acc[n] = (f32x4){0.f,0.f,0.f,0.f};
  load_ph(0);
  write_ph(0);
  __syncthreads();
  #pragma unroll
  for (int ph = 0; ph < 16; ++ph) {
    int buf = ph & 1;
    if (ph < 15) load_ph(ph + 1);
    float qdv = qd[ph];
    #pragma unroll
    for (int s = 0; s < 2; ++s) {
      bf16x8 qe = s ? qe1 : qe0;
      bf16x8 a;
      #pragma unroll
      for (int i = 0; i < 8; ++i) a[i] = (__bf16)(qdv * (float)qe[i]);
      #pragma unroll
      for (int n = 0; n < 5; ++n) {
        bf16x8 bv = *(bf16x8*)&stl[buf][(16*n + lm)*PQ + s*32 + qq*8];
        acc[n] = MFMA(a, bv, acc[n]);
      }
    }
    if (ph < 15) write_ph(buf ^ 1);
    __syncthreads();
  }
  size_t prow = (size_t)ch*CL + mb*64 + wv*16;
  #pragma unroll
  for (int j = 0; j < 4; ++j) {
    int rloc = qq*4 + j;
    #pragma unroll
    for (int n = 0; n < 4; ++n)
      atomicAdd(&pnum[(prow + rloc)*64 + 16*n + lm], acc[n][j]);
    if (lm == 0) atomicAdd(&pden[prow + rloc], acc[4][j]);
  }
}

// ---------------------------------------------------------------------------
// finalize (all chunks): out = pnum / max(pden, eps)
// ---------------------------------------------------------------------------
__global__ __launch_bounds__(256) void finalize_kernel(const float* __restrict__ pnum,
    const float* __restrict__ pden, float* __restrict__ out) {
  int idx = blockIdx.x*256 + threadIdx.x;
  int e4 = idx*4;
  int row = e4 >> 6;                  // ch*1024 + rg
  int col = e4 & 63;
  int hc = row >> 10, rg = row & 1023;
  int c = hc >> 3, h = hc & 7;
  float dinv = 1.f / fmaxf(pden[row], KEPS);
  f32x4 pv = *(const f32x4*)&pnum[e4];
  size_t ob = ((size_t)(c*CL + rg)*NH + h)*ND + col;
  f32x4 ov;
  #pragma unroll
  for (int j = 0; j < 4; ++j) ov[j] = pv[j] * dinv;
  *(f32x4*)&out[ob] = ov;
}

// ---------------------------------------------------------------------------
extern "C" void kernel_launch(void* const* d_in, const int* in_sizes, int n_in,
                              void* d_out, int out_size, void* d_ws, size_t ws_size,
                              hipStream_t stream) {
  const float* q  = (const float*)d_in[0];
  const float* k  = (const float*)d_in[1];
  const float* v  = (const float*)d_in[2];
  const float* lg = (const float*)d_in[3];
  float* out = (float*)d_out;

  float* wf    = (float*)d_ws;
  float* g_arr = wf;                       // 32768 f32
  float* gend  = g_arr + 32768;            // 32
  float* gtot  = gend + 32;                // 32
  float* pden  = gtot + 32;                // 32768 (4 chunks)
  float* pnum  = pden + 32768;             // 2,097,152 (4 chunks)
  __bf16* qgb  = (__bf16*)(pnum + 2097152);// 2,097,152 bf16 each
  __bf16* kgb  = qgb + 2097152;
  __bf16* kht  = kgb + 2097152;
  __bf16* vt   = kht + 2097152;            // 4*8*80*1024 = 2,621,440
  __bf16* st   = vt + 2621440;             // 3*8*80*4096 = 7,864,320
  // total ~42.2 MB

  hipMemsetAsync(pden, 0, (size_t)(32768 + 2097152)*sizeof(float), stream);
  gate_kernel<<<dim3(NC*NH), dim3(CL), 0, stream>>>(lg, g_arr, gend, gtot);
  convert_kernel<<<dim3(16, NH, NC), dim3(256), 0, stream>>>(q, k, v, g_arr, gend, qgb, kgb, kht, vt);
  intra_kernel<<<dim3(8, 2, 32), dim3(256), 0, stream>>>(qgb, kgb, vt, pnum, pden);
  pz_kernel<<<dim3(64, NH, 3), dim3(256), 0, stream>>>(kht, vt, st);
  scan_kernel<<<dim3(160, NH), dim3(256), 0, stream>>>(gtot, st);
  inter_partial_kernel<<<dim3(16, 4, 24), dim3(256), 0, stream>>>(qgb, st, pnum, pden);
  finalize_kernel<<<dim3(2048), dim3(256), 0, stream>>>(pnum, pden, out);
}